// Round 9
// baseline (199.269 us; speedup 1.0000x reference)
//
#include <hip/hip_runtime.h>
#include <math.h>

#define N_NODES 10000
#define N_EDGES 160000
#define RT1 157      // ceil(10000/64)
#define RTE 2500     // 160000/64
#define CONVX_T (RT1 * 64 * 32)   // 321536

static inline int ceildiv(int a, int b) { return (a + b - 1) / b; }

typedef float f32x4 __attribute__((ext_vector_type(4)));
typedef short bf16x8 __attribute__((ext_vector_type(8)));

__device__ __forceinline__ unsigned short f2bf(float f) {
  unsigned int u = __builtin_bit_cast(unsigned int, f);
  u += 0x7FFFu + ((u >> 16) & 1u);   // RNE
  return (unsigned short)(u >> 16);
}
__device__ __forceinline__ float bf2f(unsigned short h) {
  unsigned int u = ((unsigned int)h) << 16;
  return __builtin_bit_cast(float, u);
}

// ---------------- prep: rel + degree count fused ----------------
__global__ void prep1_kernel(const float* __restrict__ lu, const int* __restrict__ srcp,
                             const int* __restrict__ dstp, const float* __restrict__ tt,
                             float* __restrict__ rel, int* __restrict__ deg, int E) {
  for (int i = blockIdx.x * blockDim.x + threadIdx.x; i < E; i += gridDim.x * blockDim.x) {
    rel[i] = lu[srcp[i]] - tt[i];
    atomicAdd(&deg[dstp[i]], 1);
  }
}

__global__ void scan_kernel(const int* __restrict__ deg, int* __restrict__ rowptr, int n) {
  __shared__ int part[1024];
  const int tid = threadIdx.x;
  const int CHK = 10;
  int base = tid * CHK;
  int loc[CHK];
  int s = 0;
#pragma unroll
  for (int j = 0; j < CHK; ++j) {
    int idx = base + j;
    int v = (idx < n) ? deg[idx] : 0;
    loc[j] = s; s += v;
  }
  part[tid] = s;
  __syncthreads();
  for (int off = 1; off < 1024; off <<= 1) {
    int y = (tid >= off) ? part[tid - off] : 0;
    __syncthreads();
    part[tid] += y;
    __syncthreads();
  }
  int pre = tid ? part[tid - 1] : 0;
#pragma unroll
  for (int j = 0; j < CHK; ++j) {
    int idx = base + j;
    if (idx < n) rowptr[idx] = pre + loc[j];
  }
  if (tid == 1023) rowptr[n] = part[1023];
}

__global__ void scatter_kernel(const int* __restrict__ srcp, const int* __restrict__ dstp,
                               const int* __restrict__ rowptr, int* __restrict__ fill,
                               int* __restrict__ sortpos, int* __restrict__ srcs, int E) {
  for (int e = blockIdx.x * blockDim.x + threadIdx.x; e < E; e += gridDim.x * blockDim.x) {
    int d = dstp[e];
    int pos = atomicAdd(&fill[d], 1);
    int slot = rowptr[d] + pos;
    sortpos[e] = slot;
    srcs[slot] = srcp[e];
  }
}

// ---------------- all format conversions in ONE launch ----------------
// A frag layout (ushorts): addr(i,k)= rt*16384 + ks*2048 + rf*512 + (ir+16*kg)*8 + j
// B frag layout: addr(k,c) = (ks*NFtot + (c>>4))*512 + ((c&15)+16*kg)*8 + j
__device__ __forceinline__ void wstore(const float* __restrict__ W, unsigned short* __restrict__ out,
                                       int Nin, int n_off, int NFtot, int k, int c) {
  int gc = n_off + c;
  int ks=k>>5, kg=(k>>3)&3, j=k&7, nf=gc>>4, ic=gc&15;
  out[(size_t)(ks*NFtot+nf)*512 + (ic+16*kg)*8 + j] = f2bf(W[(size_t)k*Nin + c]);
}

__global__ void conv_all_kernel(const float* __restrict__ x, unsigned short* __restrict__ xa,
                                const float* Wq1, const float* Wk1, const float* Wv1, const float* Ws1,
                                const float* We1, const float* Wq2, const float* Wk2, const float* Wv2,
                                const float* Ws2, const float* We2,
                                const float* bq1, const float* bk1, const float* bv1, const float* bs1,
                                const float* bq2, const float* bk2, const float* bv2, const float* bs2,
                                unsigned short* W1f, unsigned short* We1f, unsigned short* W2f,
                                unsigned short* We2f, float* bcat1, float* bcat2) {
  int t0 = blockIdx.x * blockDim.x + threadIdx.x;
  if (t0 < CONVX_T) {
    int i = t0 >> 5, k8 = t0 & 31;
    union { uint4 q; unsigned short s[8]; } u;
    if (i < N_NODES) {
      const float4* px = (const float4*)(x + (size_t)i * 256 + k8 * 8);
      float4 f0 = px[0], f1 = px[1];
      u.s[0]=f2bf(f0.x); u.s[1]=f2bf(f0.y); u.s[2]=f2bf(f0.z); u.s[3]=f2bf(f0.w);
      u.s[4]=f2bf(f1.x); u.s[5]=f2bf(f1.y); u.s[6]=f2bf(f1.z); u.s[7]=f2bf(f1.w);
    } else {
      u.q = make_uint4(0,0,0,0);
    }
    int rt=i>>6, rf=(i>>4)&3, ir=i&15, ks=k8>>2, kg=k8&3;
    *(uint4*)&xa[(size_t)rt*16384 + ks*2048 + rf*512 + (ir+16*kg)*8] = u.q;
    return;
  }
  int t = t0 - CONVX_T;
  if (t < 262144) {               // W1f: 4 x 256x256
    int w = t >> 16, r = t & 65535, k = r >> 8, c = r & 255;
    const float* W = (w == 0) ? Wq1 : (w == 1) ? Wk1 : (w == 2) ? Wv1 : Ws1;
    wstore(W, W1f, 256, w * 256, 64, k, c);
  } else if (t < 327680) {        // We1f: 256x256
    int r = t - 262144, k = r >> 8, c = r & 255;
    wstore(We1, We1f, 256, 0, 16, k, c);
  } else if (t < 360448) {        // W2f: 4 x 256x32
    int r = t - 327680, w = r >> 13, r2 = r & 8191, k = r2 >> 5, c = r2 & 31;
    const float* W = (w == 0) ? Wq2 : (w == 1) ? Wk2 : (w == 2) ? Wv2 : Ws2;
    wstore(W, W2f, 32, w * 32, 8, k, c);
  } else if (t < 368640) {        // We2f: 256x32 (cols 32-63 pre-zeroed by memset)
    int r = t - 360448, k = r >> 5, c = r & 31;
    wstore(We2, We2f, 32, 0, 4, k, c);
  } else if (t < 369792) {        // biases
    int r = t - 368640;
    if (r < 1024) {
      const float* b = (r < 256) ? bq1 : (r < 512) ? bk1 : (r < 768) ? bv1 : bs1;
      bcat1[r] = b[r & 255];
    } else {
      int r2 = r - 1024;
      const float* b = (r2 < 32) ? bq2 : (r2 < 64) ? bk2 : (r2 < 96) ? bv2 : bs2;
      bcat2[r2] = b[r2 & 31];
    }
  }
}

// ---------------- BIG merged GEMM, barrier-free K-loop ----------------
// A tile fully resident in static LDS (one prologue + ONE barrier); B operands
// read directly global->VGPR each step (L2-broadcast weights). K-loop has zero
// ds_writes and zero barriers.
// bx < RTE: edge block (e1 256 cols + e2 32 cols, scatter epilogue to sorted).
// bx >= RTE: node1 block (quad-route epilogue).
__global__ __launch_bounds__(256)
void big_gemm(const unsigned short* __restrict__ xa, const unsigned short* __restrict__ W1f,
              const float* __restrict__ bcat1, float* __restrict__ qf,
              unsigned short* __restrict__ kvb, float* __restrict__ sf,
              const unsigned short* __restrict__ We1f, const unsigned short* __restrict__ We2f,
              unsigned short* __restrict__ e1b, unsigned short* __restrict__ e2b,
              const float* __restrict__ rel, const float* __restrict__ tw,
              const float* __restrict__ tb, const float* __restrict__ msg,
              const int* __restrict__ sortpos) {
  __shared__ char ldsraw[32768];        // A tile (8 K-steps x 4KB), reused by epilogue
  uint4* lds4 = (uint4*)ldsraw;
  const int tid = threadIdx.x;
  const int wid = tid >> 6, lane = tid & 63;
  const int bx = blockIdx.x;

  if (bx < RTE) {
    // ================= edge path =================
    const int rt0 = bx;
    const int phase = bx & 7;
    const int arf = tid >> 6, ar2 = tid & 63, air = ar2 & 15, akg = ar2 >> 4;
    const int aedge = rt0 * 64 + arf * 16 + air;

    // prologue: cos (ks 0-3) + msg (ks 4-7) into static LDS; ONE barrier
    // note: chunk region for K-step ks is lds4[ks*256 .. ks*256+255] (1024 + s*256 == (4+s)*256)
    {
      float rl = rel[aedge];
#pragma unroll
      for (int s = 0; s < 4; ++s) {
        int k8 = s * 4 + akg;
        const float4* twp = (const float4*)(tw + k8 * 8);
        const float4* tbp = (const float4*)(tb + k8 * 8);
        float4 w0 = twp[0], w1 = twp[1], b0 = tbp[0], b1 = tbp[1];
        union { uint4 q; unsigned short us[8]; } u;
        u.us[0]=f2bf(__cosf(rl*w0.x+b0.x)); u.us[1]=f2bf(__cosf(rl*w0.y+b0.y));
        u.us[2]=f2bf(__cosf(rl*w0.z+b0.z)); u.us[3]=f2bf(__cosf(rl*w0.w+b0.w));
        u.us[4]=f2bf(__cosf(rl*w1.x+b1.x)); u.us[5]=f2bf(__cosf(rl*w1.y+b1.y));
        u.us[6]=f2bf(__cosf(rl*w1.z+b1.z)); u.us[7]=f2bf(__cosf(rl*w1.w+b1.w));
        lds4[s * 256 + tid] = u.q;
      }
#pragma unroll
      for (int s = 0; s < 4; ++s) {
        const float4* pm = (const float4*)(msg + (size_t)aedge * 128 + (size_t)(s * 4 + akg) * 8);
        float4 f0 = pm[0], f1 = pm[1];
        union { uint4 q; unsigned short us[8]; } u;
        u.us[0]=f2bf(f0.x); u.us[1]=f2bf(f0.y); u.us[2]=f2bf(f0.z); u.us[3]=f2bf(f0.w);
        u.us[4]=f2bf(f1.x); u.us[5]=f2bf(f1.y); u.us[6]=f2bf(f1.z); u.us[7]=f2bf(f1.w);
        lds4[(4 + s) * 256 + tid] = u.q;
      }
    }
    __syncthreads();

    f32x4 acc[4][4];
    f32x4 acc2[4];
#pragma unroll
    for (int i = 0; i < 4; ++i) {
      acc2[i] = (f32x4){0.f, 0.f, 0.f, 0.f};
#pragma unroll
      for (int j = 0; j < 4; ++j) acc[i][j] = (f32x4){0.f, 0.f, 0.f, 0.f};
    }

#pragma unroll
    for (int ksi = 0; ksi < 8; ++ksi) {
      const int ks = ksi ^ phase;
      bf16x8 a[4], b[4];
      const uint4* abase = &lds4[ks * 256];   // FIX (R8 bug): valid for ALL ks
#pragma unroll
      for (int rf = 0; rf < 4; ++rf) a[rf] = *(const bf16x8*)&abase[rf * 64 + lane];
#pragma unroll
      for (int cf = 0; cf < 4; ++cf)
        b[cf] = *(const bf16x8*)(We1f + ((size_t)(ks * 16 + wid * 4 + cf)) * 512 + (size_t)lane * 8);
      bf16x8 b2 = *(const bf16x8*)(We2f + ((size_t)(ks * 4 + (wid & 1))) * 512 + (size_t)lane * 8);
#pragma unroll
      for (int rf = 0; rf < 4; ++rf)
#pragma unroll
        for (int cf = 0; cf < 4; ++cf)
          acc[rf][cf] = __builtin_amdgcn_mfma_f32_16x16x32_bf16(a[rf], b[cf], acc[rf][cf], 0, 0, 0);
      if (wid < 2) {
#pragma unroll
        for (int rf = 0; rf < 4; ++rf)
          acc2[rf] = __builtin_amdgcn_mfma_f32_16x16x32_bf16(a[rf], b2, acc2[rf], 0, 0, 0);
      }
    }

    // epilogue: scatter e1 (64x256) and e2 (64x32) rows to sorted slots
    __syncthreads();
    unsigned short* cl  = (unsigned short*)ldsraw;            // [64][72]
    unsigned short* cl2 = (unsigned short*)(ldsraw + 9216);   // [64][40]
    int* spos = (int*)(ldsraw + 14336);                       // [64]
    if (tid < 64) spos[tid] = sortpos[rt0 * 64 + tid];
    const int fr0 = (lane >> 4) * 4;
    const int fc0 = lane & 15;
    if (wid < 2) {
#pragma unroll
      for (int rf = 0; rf < 4; ++rf)
#pragma unroll
        for (int j = 0; j < 4; ++j)
          cl2[(fr0 + rf * 16 + j) * 40 + wid * 16 + fc0] = f2bf(acc2[rf][j]);
    }
    for (int pass = 0; pass < 4; ++pass) {
      if (wid == pass) {
#pragma unroll
        for (int cf = 0; cf < 4; ++cf) {
          int c = fc0 + cf * 16;
#pragma unroll
          for (int rf = 0; rf < 4; ++rf)
#pragma unroll
            for (int j = 0; j < 4; ++j)
              cl[(fr0 + rf * 16 + j) * 72 + c] = f2bf(acc[rf][cf][j]);
        }
      }
      __syncthreads();
#pragma unroll
      for (int id = tid; id < 512; id += 256) {
        int row = id >> 3, cc = (id & 7) * 8;
        int gr = spos[row];
        *(uint4*)&e1b[(size_t)gr * 256 + pass * 64 + cc] = *(const uint4*)&cl[row * 72 + cc];
      }
      __syncthreads();
    }
    {
      int row = tid >> 2, cc = (tid & 3) * 8;
      int gr = spos[row];
      *(uint4*)&e2b[(size_t)gr * 32 + cc] = *(const uint4*)&cl2[row * 40 + cc];
    }
  } else {
    // ================= node1 path =================
    const int idx = bx - RTE;
    const int rt0 = idx % RT1;
    const int y = idx / RT1;
    const int phase = rt0 & 7;
    const int n0f = y * 16;

    // prologue: all 8 A K-steps resident (32KB); ONE barrier
#pragma unroll
    for (int s = 0; s < 8; ++s)
      lds4[s * 256 + tid] = *(const uint4*)(xa + (size_t)rt0 * 16384 + (size_t)s * 2048 + (size_t)tid * 8);
    __syncthreads();

    f32x4 acc[4][4];
#pragma unroll
    for (int i = 0; i < 4; ++i)
#pragma unroll
      for (int j = 0; j < 4; ++j) acc[i][j] = (f32x4){0.f, 0.f, 0.f, 0.f};

#pragma unroll
    for (int ksi = 0; ksi < 8; ++ksi) {
      const int ks = ksi ^ phase;
      bf16x8 a[4], b[4];
#pragma unroll
      for (int rf = 0; rf < 4; ++rf) a[rf] = *(const bf16x8*)&lds4[ks * 256 + rf * 64 + lane];
#pragma unroll
      for (int cf = 0; cf < 4; ++cf)
        b[cf] = *(const bf16x8*)(W1f + ((size_t)(ks * 64 + n0f + wid * 4 + cf)) * 512 + (size_t)lane * 8);
#pragma unroll
      for (int rf = 0; rf < 4; ++rf)
#pragma unroll
        for (int cf = 0; cf < 4; ++cf)
          acc[rf][cf] = __builtin_amdgcn_mfma_f32_16x16x32_bf16(a[rf], b[cf], acc[rf][cf], 0, 0, 0);
    }

    // quad-routed epilogue: y0 -> qf f32 | y1,y2 -> kvb bf16 | y3 -> sf f32
    bool bf16path;
    void* dstp_; int cstr_, dc0_, bcol0_;
    if (y == 0)      { bf16path = false; dstp_ = qf;  cstr_ = 256; dc0_ = 0;   bcol0_ = 0; }
    else if (y == 1) { bf16path = true;  dstp_ = kvb; cstr_ = 512; dc0_ = 0;   bcol0_ = 256; }
    else if (y == 2) { bf16path = true;  dstp_ = kvb; cstr_ = 512; dc0_ = 256; bcol0_ = 512; }
    else             { bf16path = false; dstp_ = sf;  cstr_ = 256; dc0_ = 0;   bcol0_ = 768; }
    const int fr0 = (lane >> 4) * 4;
    const int fc0 = lane & 15;
    if (!bf16path) {
      float* dst = (float*)dstp_;
      const int row0 = rt0 * 64 + fr0;
      const int cb2 = wid * 64 + fc0;
#pragma unroll
      for (int cf = 0; cf < 4; ++cf) {
        int c = cb2 + cf * 16;
        float bv = bcat1[bcol0_ + c];
#pragma unroll
        for (int rf = 0; rf < 4; ++rf) {
#pragma unroll
          for (int j = 0; j < 4; ++j) {
            int r = row0 + rf * 16 + j;
            if (r < N_NODES) dst[(size_t)r * cstr_ + c] = acc[rf][cf][j] + bv;
          }
        }
      }
    } else {
      __syncthreads();
      unsigned short* cl = (unsigned short*)ldsraw;   // [64][72]
      unsigned short* dst = (unsigned short*)dstp_;
      for (int pass = 0; pass < 4; ++pass) {
        if (wid == pass) {
#pragma unroll
          for (int cf = 0; cf < 4; ++cf) {
            int c = fc0 + cf * 16;
            float bv = bcat1[bcol0_ + pass * 64 + c];
#pragma unroll
            for (int rf = 0; rf < 4; ++rf)
#pragma unroll
              for (int j = 0; j < 4; ++j)
                cl[(fr0 + rf * 16 + j) * 72 + c] = f2bf(acc[rf][cf][j] + bv);
          }
        }
        __syncthreads();
#pragma unroll
        for (int id = tid; id < 512; id += 256) {
          int row = id >> 3, cc = (id & 7) * 8;
          int gr = rt0 * 64 + row;
          if (gr < N_NODES)
            *(uint4*)&dst[(size_t)gr * cstr_ + dc0_ + pass * 64 + cc] = *(const uint4*)&cl[row * 72 + cc];
        }
        __syncthreads();
      }
    }
  }
}

// ---------------- node2 GEMM: LDS-free, barrier-free (FIX R8: was 64KB into 32KB) ----
// A read direct from ha (frag-linear, 1KB/wave coalesced, L2-resident); B from W2f.
__global__ __launch_bounds__(256)
void gemm_node2(const unsigned short* __restrict__ ha, const unsigned short* __restrict__ W2f,
                const float* __restrict__ bcat2, float* __restrict__ qkvs2) {
  const int tid = threadIdx.x;
  const int wid = tid >> 6, lane = tid & 63;
  const int wr = wid >> 1, wc = wid & 1;
  const int rt0 = blockIdx.x * 2;
  int rtA = rt0 + wr;
  if (rtA >= RT1) rtA = RT1 - 1;   // duplicate compute; stores guarded below

  f32x4 acc[4][4];
#pragma unroll
  for (int i = 0; i < 4; ++i)
#pragma unroll
    for (int j = 0; j < 4; ++j) acc[i][j] = (f32x4){0.f, 0.f, 0.f, 0.f};

#pragma unroll
  for (int ks = 0; ks < 8; ++ks) {
    bf16x8 a[4], b[4];
#pragma unroll
    for (int rf = 0; rf < 4; ++rf)
      a[rf] = *(const bf16x8*)(ha + (size_t)rtA * 16384 + (size_t)ks * 2048 + (size_t)(rf * 64 + lane) * 8);
#pragma unroll
    for (int cf = 0; cf < 4; ++cf)
      b[cf] = *(const bf16x8*)(W2f + ((size_t)(ks * 8 + wc * 4 + cf)) * 512 + (size_t)lane * 8);
#pragma unroll
    for (int rf = 0; rf < 4; ++rf)
#pragma unroll
      for (int cf = 0; cf < 4; ++cf)
        acc[rf][cf] = __builtin_amdgcn_mfma_f32_16x16x32_bf16(a[rf], b[cf], acc[rf][cf], 0, 0, 0);
  }

  const int row0 = (rt0 + wr) * 64 + ((lane >> 4) * 4);
  const int cb2 = wc * 64 + (lane & 15);
#pragma unroll
  for (int cf = 0; cf < 4; ++cf) {
    int c = cb2 + cf * 16;
    float bv = bcat2[c];
#pragma unroll
    for (int rf = 0; rf < 4; ++rf) {
#pragma unroll
      for (int j = 0; j < 4; ++j) {
        int r = row0 + rf * 16 + j;
        if (r < N_NODES) qkvs2[(size_t)r * 128 + c] = acc[rf][cf][j] + bv;
      }
    }
  }
}

// ---------------- attention layer 1: 2-edge unroll, dual online state ----------------
__global__ __launch_bounds__(64)
void attn1_kernel(const float* __restrict__ qf, const unsigned short* __restrict__ kvb,
                  const float* __restrict__ sf, const unsigned short* __restrict__ e1b,
                  const int* __restrict__ srcs, const int* __restrict__ rowptr,
                  unsigned short* __restrict__ ha) {
  const int n = blockIdx.x;
  const int lane = threadIdx.x;
  const int h = lane >> 3;
  const int c0 = (lane & 7) * 4;
  const int off = h * 32 + c0;
  const int beg = rowptr[n], end = rowptr[n + 1];
  const float4 q = *(const float4*)&qf[(size_t)n * 256 + off];
  float m0 = -INFINITY, d0 = 0.f, x0 = 0.f, x1 = 0.f, x2 = 0.f, x3 = 0.f;
  float m1 = -INFINITY, d1 = 0.f, y0 = 0.f, y1 = 0.f, y2 = 0.f, y3 = 0.f;
  int i = beg;
  for (; i + 1 < end; i += 2) {
    const int sA = srcs[i], sB = srcs[i + 1];
    ushort4 evA = *(const ushort4*)&e1b[(size_t)i * 256 + off];
    ushort4 kkA = *(const ushort4*)&kvb[(size_t)sA * 512 + off];
    ushort4 vvA = *(const ushort4*)&kvb[(size_t)sA * 512 + 256 + off];
    ushort4 evB = *(const ushort4*)&e1b[(size_t)(i + 1) * 256 + off];
    ushort4 kkB = *(const ushort4*)&kvb[(size_t)sB * 512 + off];
    ushort4 vvB = *(const ushort4*)&kvb[(size_t)sB * 512 + 256 + off];
    float eA0=bf2f(evA.x), eA1=bf2f(evA.y), eA2=bf2f(evA.z), eA3=bf2f(evA.w);
    float eB0=bf2f(evB.x), eB1=bf2f(evB.y), eB2=bf2f(evB.z), eB3=bf2f(evB.w);
    float pA = q.x*(bf2f(kkA.x)+eA0) + q.y*(bf2f(kkA.y)+eA1) + q.z*(bf2f(kkA.z)+eA2) + q.w*(bf2f(kkA.w)+eA3);
    float pB = q.x*(bf2f(kkB.x)+eB0) + q.y*(bf2f(kkB.y)+eB1) + q.z*(bf2f(kkB.z)+eB2) + q.w*(bf2f(kkB.w)+eB3);
    pA += __shfl_xor(pA, 1); pA += __shfl_xor(pA, 2); pA += __shfl_xor(pA, 4);
    pB += __shfl_xor(pB, 1); pB += __shfl_xor(pB, 2); pB += __shfl_xor(pB, 4);
    pA *= 0.17677669529663687f;
    pB *= 0.17677669529663687f;
    {
      const float mn = fmaxf(m0, pA);
      const float sc = __expf(m0 - mn), w = __expf(pA - mn);
      d0 = d0 * sc + w;
      x0 = x0 * sc + w * (bf2f(vvA.x) + eA0);
      x1 = x1 * sc + w * (bf2f(vvA.y) + eA1);
      x2 = x2 * sc + w * (bf2f(vvA.z) + eA2);
      x3 = x3 * sc + w * (bf2f(vvA.w) + eA3);
      m0 = mn;
    }
    {
      const float mn = fmaxf(m1, pB);
      const float sc = __expf(m1 - mn), w = __expf(pB - mn);
      d1 = d1 * sc + w;
      y0 = y0 * sc + w * (bf2f(vvB.x) + eB0);
      y1 = y1 * sc + w * (bf2f(vvB.y) + eB1);
      y2 = y2 * sc + w * (bf2f(vvB.z) + eB2);
      y3 = y3 * sc + w * (bf2f(vvB.w) + eB3);
      m1 = mn;
    }
  }
  if (i < end) {
    const int sA = srcs[i];
    ushort4 evA = *(const ushort4*)&e1b[(size_t)i * 256 + off];
    ushort4 kkA = *(const ushort4*)&kvb[(size_t)sA * 512 + off];
    ushort4 vvA = *(const ushort4*)&kvb[(size_t)sA * 512 + 256 + off];
    float eA0=bf2f(evA.x), eA1=bf2f(evA.y), eA2=bf2f(evA.z), eA3=bf2f(evA.w);
    float pA = q.x*(bf2f(kkA.x)+eA0) + q.y*(bf2f(kkA.y)+eA1) + q.z*(bf2f(kkA.z)+eA2) + q.w*(bf2f(kkA.w)+eA3);
    pA += __shfl_xor(pA, 1); pA += __shfl_xor(pA, 2); pA += __shfl_xor(pA, 4);
    pA *= 0.17677669529663687f;
    const float mn = fmaxf(m0, pA);
    const float sc = __expf(m0 - mn), w = __expf(pA - mn);
    d0 = d0 * sc + w;
    x0 = x0 * sc + w * (bf2f(vvA.x) + eA0);
    x1 = x1 * sc + w * (bf2f(vvA.y) + eA1);
    x2 = x2 * sc + w * (bf2f(vvA.z) + eA2);
    x3 = x3 * sc + w * (bf2f(vvA.w) + eA3);
    m0 = mn;
  }
  float den = d0, a0 = x0, a1 = x1, a2 = x2, a3 = x3;
  if (m1 != -INFINITY) {
    const float M = fmaxf(m0, m1);
    const float sA = __expf(m0 - M), sB = __expf(m1 - M);
    den = d0 * sA + d1 * sB;
    a0 = x0 * sA + y0 * sB; a1 = x1 * sA + y1 * sB;
    a2 = x2 * sA + y2 * sB; a3 = x3 * sA + y3 * sB;
  }
  const float inv = 1.f / (den + 1e-16f);
  const float4 sk = *(const float4*)&sf[(size_t)n * 256 + off];
  float o0 = fmaxf(a0 * inv + sk.x, 0.f);
  float o1 = fmaxf(a1 * inv + sk.y, 0.f);
  float o2 = fmaxf(a2 * inv + sk.z, 0.f);
  float o3 = fmaxf(a3 * inv + sk.w, 0.f);
  int rt = n >> 6, rf = (n >> 4) & 3, ir = n & 15;
  int kg = (lane & 7) >> 1, jj = 4 * (lane & 1);
  ushort4 w4;
  w4.x = f2bf(o0); w4.y = f2bf(o1); w4.z = f2bf(o2); w4.w = f2bf(o3);
  *(ushort4*)&ha[(size_t)rt * 16384 + h * 2048 + rf * 512 + (ir + 16 * kg) * 8 + jj] = w4;
}

// ---------------- attention layer 2: 2-edge unroll ----------------
__global__ __launch_bounds__(64)
void attn2_kernel(const float* __restrict__ qkvs2, const unsigned short* __restrict__ e2b,
                  const int* __restrict__ srcs, const int* __restrict__ rowptr,
                  float* __restrict__ outp) {
  const int n = blockIdx.x;
  const int tid = threadIdx.x;
  const int c = tid & 31;
  const int beg = rowptr[n], end = rowptr[n + 1];
  const float qv = qkvs2[(size_t)n * 128 + c];
  float m0 = -INFINITY, d0 = 0.f, x0 = 0.f;
  float m1 = -INFINITY, d1 = 0.f, y0 = 0.f;
  int i = beg;
  for (; i + 1 < end; i += 2) {
    const int sA = srcs[i], sB = srcs[i + 1];
    const float eA = bf2f(e2b[(size_t)i * 32 + c]);
    const float eB = bf2f(e2b[(size_t)(i + 1) * 32 + c]);
    float pA = qv * (qkvs2[(size_t)sA * 128 + 32 + c] + eA);
    float pB = qv * (qkvs2[(size_t)sB * 128 + 32 + c] + eB);
    const float vA = qkvs2[(size_t)sA * 128 + 64 + c] + eA;
    const float vB = qkvs2[(size_t)sB * 128 + 64 + c] + eB;
#pragma unroll
    for (int off = 16; off; off >>= 1) pA += __shfl_xor(pA, off);
#pragma unroll
    for (int off = 16; off; off >>= 1) pB += __shfl_xor(pB, off);
    pA *= 0.17677669529663687f;
    pB *= 0.17677669529663687f;
    {
      const float mn = fmaxf(m0, pA);
      const float sc = __expf(m0 - mn), w = __expf(pA - mn);
      d0 = d0 * sc + w; x0 = x0 * sc + w * vA; m0 = mn;
    }
    {
      const float mn = fmaxf(m1, pB);
      const float sc = __expf(m1 - mn), w = __expf(pB - mn);
      d1 = d1 * sc + w; y0 = y0 * sc + w * vB; m1 = mn;
    }
  }
  if (i < end) {
    const int sA = srcs[i];
    const float eA = bf2f(e2b[(size_t)i * 32 + c]);
    float pA = qv * (qkvs2[(size_t)sA * 128 + 32 + c] + eA);
    const float vA = qkvs2[(size_t)sA * 128 + 64 + c] + eA;
#pragma unroll
    for (int off = 16; off; off >>= 1) pA += __shfl_xor(pA, off);
    pA *= 0.17677669529663687f;
    const float mn = fmaxf(m0, pA);
    const float sc = __expf(m0 - mn), w = __expf(pA - mn);
    d0 = d0 * sc + w; x0 = x0 * sc + w * vA; m0 = mn;
  }
  float den = d0, acc = x0;
  if (m1 != -INFINITY) {
    const float M = fmaxf(m0, m1);
    const float sA = __expf(m0 - M), sB = __expf(m1 - M);
    den = d0 * sA + d1 * sB;
    acc = x0 * sA + y0 * sB;
  }
  if (tid < 32) {
    float o = acc / (den + 1e-16f) + qkvs2[(size_t)n * 128 + 96 + c];
    outp[(size_t)n * 32 + c] = fmaxf(o, 0.f);
  }
}

// ---------------- launcher ----------------
extern "C" void kernel_launch(void* const* d_in, const int* in_sizes, int n_in,
                              void* d_out, int out_size, void* d_ws, size_t ws_size,
                              hipStream_t stream) {
  const float* x   = (const float*)d_in[0];
  const float* lu  = (const float*)d_in[1];
  const int*   ei  = (const int*)d_in[2];
  const float* tt  = (const float*)d_in[3];
  const float* msg = (const float*)d_in[4];
  const float* tw  = (const float*)d_in[5];
  const float* tb  = (const float*)d_in[6];
  const float* Wq1 = (const float*)d_in[7];  const float* bq1 = (const float*)d_in[8];
  const float* Wk1 = (const float*)d_in[9];  const float* bk1 = (const float*)d_in[10];
  const float* Wv1 = (const float*)d_in[11]; const float* bv1 = (const float*)d_in[12];
  const float* We1 = (const float*)d_in[13];
  const float* Ws1 = (const float*)d_in[14]; const float* bs1 = (const float*)d_in[15];
  const float* Wq2 = (const float*)d_in[16]; const float* bq2 = (const float*)d_in[17];
  const float* Wk2 = (const float*)d_in[18]; const float* bk2 = (const float*)d_in[19];
  const float* Wv2 = (const float*)d_in[20]; const float* bv2 = (const float*)d_in[21];
  const float* We2 = (const float*)d_in[22];
  const float* Ws2 = (const float*)d_in[23]; const float* bs2 = (const float*)d_in[24];

  const int* srcp = ei;
  const int* dstp = ei + N_EDGES;

  char* p = (char*)d_ws;
  auto alloc = [&](size_t bytes) -> char* {
    char* r = p;
    p += (bytes + 255) & ~(size_t)255;
    return r;
  };
  int*   deg     = (int*)alloc((size_t)N_NODES * 4);
  int*   fill    = (int*)alloc((size_t)N_NODES * 4);
  int*   rowptr  = (int*)alloc((size_t)(N_NODES + 1) * 4);
  int*   sortpos = (int*)alloc((size_t)N_EDGES * 4);
  int*   srcs    = (int*)alloc((size_t)N_EDGES * 4);
  float* rel     = (float*)alloc((size_t)N_EDGES * 4);
  unsigned short* xa   = (unsigned short*)alloc((size_t)RT1 * 32768);
  unsigned short* W1f  = (unsigned short*)alloc((size_t)8 * 64 * 1024);
  unsigned short* We1f = (unsigned short*)alloc((size_t)8 * 16 * 1024);
  unsigned short* W2f  = (unsigned short*)alloc((size_t)8 * 8 * 1024);
  unsigned short* We2f = (unsigned short*)alloc((size_t)8 * 4 * 1024);
  float* bcat1  = (float*)alloc(1024 * 4);
  float* bcat2  = (float*)alloc(128 * 4);
  float* qf     = (float*)alloc((size_t)N_NODES * 256 * 4);
  unsigned short* kvb = (unsigned short*)alloc((size_t)N_NODES * 512 * 2);
  float* sf     = (float*)alloc((size_t)N_NODES * 256 * 4);
  unsigned short* e1b = (unsigned short*)alloc((size_t)N_EDGES * 256 * 2);   // 82 MB
  unsigned short* ha  = (unsigned short*)alloc((size_t)RT1 * 32768);
  float* qkvs2  = (float*)alloc((size_t)N_NODES * 128 * 4);
  unsigned short* e2b = (unsigned short*)alloc((size_t)N_EDGES * 32 * 2);
  float* outp   = (float*)d_out;

  hipMemsetAsync(deg, 0, (size_t)N_NODES * 4, stream);
  hipMemsetAsync(fill, 0, (size_t)N_NODES * 4, stream);
  hipMemsetAsync(ha + (size_t)(RT1 - 1) * 16384, 0, 32768, stream);  // zero pad rows 10000-10047

  prep1_kernel<<<625, 256, 0, stream>>>(lu, srcp, dstp, tt, rel, deg, N_EDGES);
  scan_kernel<<<1, 1024, 0, stream>>>(deg, rowptr, N_NODES);
  scatter_kernel<<<625, 256, 0, stream>>>(srcp, dstp, rowptr, fill, sortpos, srcs, N_EDGES);

  conv_all_kernel<<<ceildiv(CONVX_T + 369792, 256), 256, 0, stream>>>(
      x, xa, Wq1, Wk1, Wv1, Ws1, We1, Wq2, Wk2, Wv2, Ws2, We2,
      bq1, bk1, bv1, bs1, bq2, bk2, bv2, bs2,
      W1f, We1f, W2f, We2f, bcat1, bcat2);

  // merged: 2500 edge blocks (e1+e2) + 628 node1 blocks, barrier-free K-loops
  big_gemm<<<RTE + RT1 * 4, 256, 0, stream>>>(
      xa, W1f, bcat1, qf, kvb, sf, We1f, We2f, e1b, e2b,
      rel, tw, tb, msg, sortpos);

  attn1_kernel<<<N_NODES, 64, 0, stream>>>(qf, kvb, sf, e1b, srcs, rowptr, ha);
  gemm_node2<<<ceildiv(RT1, 2), 256, 0, stream>>>(ha, W2f, bcat2, qkvs2);
  attn2_kernel<<<N_NODES, 64, 0, stream>>>(qkvs2, e2b, srcs, rowptr, outp);
}

// Round 10
// 189.928 us; speedup vs baseline: 1.0492x; 1.0492x over previous
//
#include <hip/hip_runtime.h>
#include <math.h>

#define N_NODES 10000
#define N_EDGES 160000
#define RT1 157      // ceil(10000/64)
#define RTE 2500     // 160000/64
#define CONVX_T (RT1 * 64 * 32)   // 321536

static inline int ceildiv(int a, int b) { return (a + b - 1) / b; }

typedef float f32x4 __attribute__((ext_vector_type(4)));
typedef short bf16x8 __attribute__((ext_vector_type(8)));

__device__ __forceinline__ unsigned short f2bf(float f) {
  unsigned int u = __builtin_bit_cast(unsigned int, f);
  u += 0x7FFFu + ((u >> 16) & 1u);   // RNE
  return (unsigned short)(u >> 16);
}
__device__ __forceinline__ float bf2f(unsigned short h) {
  unsigned int u = ((unsigned int)h) << 16;
  return __builtin_bit_cast(float, u);
}

// ---------------- prep: rel + degree count fused ----------------
__global__ void prep1_kernel(const float* __restrict__ lu, const int* __restrict__ srcp,
                             const int* __restrict__ dstp, const float* __restrict__ tt,
                             float* __restrict__ rel, int* __restrict__ deg, int E) {
  for (int i = blockIdx.x * blockDim.x + threadIdx.x; i < E; i += gridDim.x * blockDim.x) {
    rel[i] = lu[srcp[i]] - tt[i];
    atomicAdd(&deg[dstp[i]], 1);
  }
}

__global__ void scan_kernel(const int* __restrict__ deg, int* __restrict__ rowptr, int n) {
  __shared__ int part[1024];
  const int tid = threadIdx.x;
  const int CHK = 10;
  int base = tid * CHK;
  int loc[CHK];
  int s = 0;
#pragma unroll
  for (int j = 0; j < CHK; ++j) {
    int idx = base + j;
    int v = (idx < n) ? deg[idx] : 0;
    loc[j] = s; s += v;
  }
  part[tid] = s;
  __syncthreads();
  for (int off = 1; off < 1024; off <<= 1) {
    int y = (tid >= off) ? part[tid - off] : 0;
    __syncthreads();
    part[tid] += y;
    __syncthreads();
  }
  int pre = tid ? part[tid - 1] : 0;
#pragma unroll
  for (int j = 0; j < CHK; ++j) {
    int idx = base + j;
    if (idx < n) rowptr[idx] = pre + loc[j];
  }
  if (tid == 1023) rowptr[n] = part[1023];
}

__global__ void scatter_kernel(const int* __restrict__ srcp, const int* __restrict__ dstp,
                               const int* __restrict__ rowptr, int* __restrict__ fill,
                               int* __restrict__ sortpos, int* __restrict__ srcs, int E) {
  for (int e = blockIdx.x * blockDim.x + threadIdx.x; e < E; e += gridDim.x * blockDim.x) {
    int d = dstp[e];
    int pos = atomicAdd(&fill[d], 1);
    int slot = rowptr[d] + pos;
    sortpos[e] = slot;
    srcs[slot] = srcp[e];
  }
}

// ---------------- all format conversions in ONE launch ----------------
// A frag layout (ushorts): addr(i,k)= rt*16384 + ks*2048 + rf*512 + (ir+16*kg)*8 + j
// B frag layout: addr(k,c) = (ks*NFtot + (c>>4))*512 + ((c&15)+16*kg)*8 + j
__device__ __forceinline__ void wstore(const float* __restrict__ W, unsigned short* __restrict__ out,
                                       int Nin, int n_off, int NFtot, int k, int c) {
  int gc = n_off + c;
  int ks=k>>5, kg=(k>>3)&3, j=k&7, nf=gc>>4, ic=gc&15;
  out[(size_t)(ks*NFtot+nf)*512 + (ic+16*kg)*8 + j] = f2bf(W[(size_t)k*Nin + c]);
}

__global__ void conv_all_kernel(const float* __restrict__ x, unsigned short* __restrict__ xa,
                                const float* Wq1, const float* Wk1, const float* Wv1, const float* Ws1,
                                const float* We1, const float* Wq2, const float* Wk2, const float* Wv2,
                                const float* Ws2, const float* We2,
                                const float* bq1, const float* bk1, const float* bv1, const float* bs1,
                                const float* bq2, const float* bk2, const float* bv2, const float* bs2,
                                unsigned short* W1f, unsigned short* We1f, unsigned short* W2f,
                                unsigned short* We2f, float* bcat1, float* bcat2) {
  int t0 = blockIdx.x * blockDim.x + threadIdx.x;
  if (t0 < CONVX_T) {
    int i = t0 >> 5, k8 = t0 & 31;
    union { uint4 q; unsigned short s[8]; } u;
    if (i < N_NODES) {
      const float4* px = (const float4*)(x + (size_t)i * 256 + k8 * 8);
      float4 f0 = px[0], f1 = px[1];
      u.s[0]=f2bf(f0.x); u.s[1]=f2bf(f0.y); u.s[2]=f2bf(f0.z); u.s[3]=f2bf(f0.w);
      u.s[4]=f2bf(f1.x); u.s[5]=f2bf(f1.y); u.s[6]=f2bf(f1.z); u.s[7]=f2bf(f1.w);
    } else {
      u.q = make_uint4(0,0,0,0);
    }
    int rt=i>>6, rf=(i>>4)&3, ir=i&15, ks=k8>>2, kg=k8&3;
    *(uint4*)&xa[(size_t)rt*16384 + ks*2048 + rf*512 + (ir+16*kg)*8] = u.q;
    return;
  }
  int t = t0 - CONVX_T;
  if (t < 262144) {               // W1f: 4 x 256x256
    int w = t >> 16, r = t & 65535, k = r >> 8, c = r & 255;
    const float* W = (w == 0) ? Wq1 : (w == 1) ? Wk1 : (w == 2) ? Wv1 : Ws1;
    wstore(W, W1f, 256, w * 256, 64, k, c);
  } else if (t < 327680) {        // We1f: 256x256
    int r = t - 262144, k = r >> 8, c = r & 255;
    wstore(We1, We1f, 256, 0, 16, k, c);
  } else if (t < 360448) {        // W2f: 4 x 256x32
    int r = t - 327680, w = r >> 13, r2 = r & 8191, k = r2 >> 5, c = r2 & 31;
    const float* W = (w == 0) ? Wq2 : (w == 1) ? Wk2 : (w == 2) ? Wv2 : Ws2;
    wstore(W, W2f, 32, w * 32, 8, k, c);
  } else if (t < 368640) {        // We2f: 256x32 (cols 32-63 pre-zeroed by memset)
    int r = t - 360448, k = r >> 5, c = r & 31;
    wstore(We2, We2f, 32, 0, 4, k, c);
  } else if (t < 369792) {        // biases
    int r = t - 368640;
    if (r < 1024) {
      const float* b = (r < 256) ? bq1 : (r < 512) ? bk1 : (r < 768) ? bv1 : bs1;
      bcat1[r] = b[r & 255];
    } else {
      int r2 = r - 1024;
      const float* b = (r2 < 32) ? bq2 : (r2 < 64) ? bk2 : (r2 < 96) ? bv2 : bs2;
      bcat2[r2] = b[r2 & 31];
    }
  }
}

// ---------------- BIG merged GEMM: 512 threads, 8 waves, 64x32 per wave ----------------
// acc footprint halved (8 frags = 32 regs/wave) vs R9's 64x64 waves -> target
// ~5 waves/SIMD occupancy so the direct-global B-load latency is hidden by TLP.
// A tile resident in LDS (one barrier); B global->VGPR per step (L2 broadcast).
// bx < RTE: edge block (e1 8x32 cols; e2 frags on waves 0,1; scatter epilogue).
// bx >= RTE: node1 block (y = quad-group; 8 waves cover its 256 cols).
__global__ __launch_bounds__(512)
void big_gemm(const unsigned short* __restrict__ xa, const unsigned short* __restrict__ W1f,
              const float* __restrict__ bcat1, float* __restrict__ qf,
              unsigned short* __restrict__ kvb, float* __restrict__ sf,
              const unsigned short* __restrict__ We1f, const unsigned short* __restrict__ We2f,
              unsigned short* __restrict__ e1b, unsigned short* __restrict__ e2b,
              const float* __restrict__ rel, const float* __restrict__ tw,
              const float* __restrict__ tb, const float* __restrict__ msg,
              const int* __restrict__ sortpos) {
  __shared__ char ldsraw[32768];        // A tile (8 K-steps x 4KB); reused by epilogue
  uint4* lds4 = (uint4*)ldsraw;
  const int tid = threadIdx.x;
  const int wid = tid >> 6, lane = tid & 63;
  const int bx = blockIdx.x;
  const int fr0 = (lane >> 4) * 4;
  const int fc0 = lane & 15;

  if (bx < RTE) {
    // ================= edge path =================
    const int rt0 = bx;
    const int phase = bx & 7;
    // prologue: 2048 A-chunks over 512 threads (4 each: 2 cos + 2 msg)
    {
      const int rem = tid & 255;               // chunk-in-step
      const int ksh = tid >> 8;                // 0 or 1
      const int arf = rem >> 6, ar2 = rem & 63, air = ar2 & 15, akg = ar2 >> 4;
      const int aedge = rt0 * 64 + arf * 16 + air;
      float rl = rel[aedge];
#pragma unroll
      for (int s = 0; s < 2; ++s) {
        int ks = ksh + s * 2;                  // cos K-steps 0..3
        int k8 = ks * 4 + akg;
        const float4* twp = (const float4*)(tw + k8 * 8);
        const float4* tbp = (const float4*)(tb + k8 * 8);
        float4 w0 = twp[0], w1 = twp[1], b0 = tbp[0], b1 = tbp[1];
        union { uint4 q; unsigned short us[8]; } u;
        u.us[0]=f2bf(__cosf(rl*w0.x+b0.x)); u.us[1]=f2bf(__cosf(rl*w0.y+b0.y));
        u.us[2]=f2bf(__cosf(rl*w0.z+b0.z)); u.us[3]=f2bf(__cosf(rl*w0.w+b0.w));
        u.us[4]=f2bf(__cosf(rl*w1.x+b1.x)); u.us[5]=f2bf(__cosf(rl*w1.y+b1.y));
        u.us[6]=f2bf(__cosf(rl*w1.z+b1.z)); u.us[7]=f2bf(__cosf(rl*w1.w+b1.w));
        lds4[ks * 256 + rem] = u.q;
      }
#pragma unroll
      for (int s = 0; s < 2; ++s) {
        int ks = 4 + ksh + s * 2;              // msg K-steps 4..7
        int k8 = ks * 4 + akg;                 // 16..31
        const float4* pm = (const float4*)(msg + (size_t)aedge * 128 + (size_t)(k8 - 16) * 8);
        float4 f0 = pm[0], f1 = pm[1];
        union { uint4 q; unsigned short us[8]; } u;
        u.us[0]=f2bf(f0.x); u.us[1]=f2bf(f0.y); u.us[2]=f2bf(f0.z); u.us[3]=f2bf(f0.w);
        u.us[4]=f2bf(f1.x); u.us[5]=f2bf(f1.y); u.us[6]=f2bf(f1.z); u.us[7]=f2bf(f1.w);
        lds4[ks * 256 + rem] = u.q;
      }
    }
    __syncthreads();

    f32x4 acc[4][2];
    f32x4 acc2[4];
#pragma unroll
    for (int i = 0; i < 4; ++i) {
      acc2[i] = (f32x4){0.f, 0.f, 0.f, 0.f};
#pragma unroll
      for (int j = 0; j < 2; ++j) acc[i][j] = (f32x4){0.f, 0.f, 0.f, 0.f};
    }

#pragma unroll
    for (int ksi = 0; ksi < 8; ++ksi) {
      const int ks = ksi ^ phase;
      bf16x8 a[4], b[2];
#pragma unroll
      for (int rf = 0; rf < 4; ++rf) a[rf] = *(const bf16x8*)&lds4[ks * 256 + rf * 64 + lane];
#pragma unroll
      for (int cf = 0; cf < 2; ++cf)
        b[cf] = *(const bf16x8*)(We1f + ((size_t)(ks * 16 + wid * 2 + cf)) * 512 + (size_t)lane * 8);
#pragma unroll
      for (int rf = 0; rf < 4; ++rf)
#pragma unroll
        for (int cf = 0; cf < 2; ++cf)
          acc[rf][cf] = __builtin_amdgcn_mfma_f32_16x16x32_bf16(a[rf], b[cf], acc[rf][cf], 0, 0, 0);
      if (wid < 2) {
        bf16x8 b2 = *(const bf16x8*)(We2f + ((size_t)(ks * 4 + wid)) * 512 + (size_t)lane * 8);
#pragma unroll
        for (int rf = 0; rf < 4; ++rf)
          acc2[rf] = __builtin_amdgcn_mfma_f32_16x16x32_bf16(a[rf], b2, acc2[rf], 0, 0, 0);
      }
    }

    // epilogue: scatter e1 (64x256) + e2 (64x32) rows to sorted slots
    __syncthreads();
    unsigned short* cl  = (unsigned short*)ldsraw;            // [64][72]
    unsigned short* cl2 = (unsigned short*)(ldsraw + 9216);   // [64][40]
    int* spos = (int*)(ldsraw + 14336);                       // [64]
    if (tid < 64) spos[tid] = sortpos[rt0 * 64 + tid];
    if (wid < 2) {                                            // e2: wave w -> cols w*16+fc0
#pragma unroll
      for (int rf = 0; rf < 4; ++rf)
#pragma unroll
        for (int j = 0; j < 4; ++j)
          cl2[(fr0 + rf * 16 + j) * 40 + wid * 16 + fc0] = f2bf(acc2[rf][j]);
    }
    for (int pass = 0; pass < 4; ++pass) {
      if ((wid >> 1) == pass) {                // waves 2p,2p+1 own cols [p*64, p*64+64)
#pragma unroll
        for (int cf = 0; cf < 2; ++cf) {
          int c = (wid & 1) * 32 + cf * 16 + fc0;
#pragma unroll
          for (int rf = 0; rf < 4; ++rf)
#pragma unroll
            for (int j = 0; j < 4; ++j)
              cl[(fr0 + rf * 16 + j) * 72 + c] = f2bf(acc[rf][cf][j]);
        }
      }
      __syncthreads();
      {
        int row = tid >> 3, cc = (tid & 7) * 8;   // 512 chunks exactly
        int gr = spos[row];
        *(uint4*)&e1b[(size_t)gr * 256 + pass * 64 + cc] = *(const uint4*)&cl[row * 72 + cc];
      }
      __syncthreads();
    }
    if (tid < 256) {
      int row = tid >> 2, cc = (tid & 3) * 8;
      int gr = spos[row];
      *(uint4*)&e2b[(size_t)gr * 32 + cc] = *(const uint4*)&cl2[row * 40 + cc];
    }
  } else {
    // ================= node1 path =================
    const int idx = bx - RTE;
    const int rt0 = idx % RT1;
    const int y = idx / RT1;                   // 0..3: q | k | v | s
    const int phase = rt0 & 7;

    // prologue: all 8 A K-steps (32KB linear copy); ONE barrier
#pragma unroll
    for (int s = 0; s < 4; ++s)
      lds4[tid + s * 512] = *(const uint4*)(xa + (size_t)rt0 * 16384 + (size_t)(tid + s * 512) * 8);
    __syncthreads();

    f32x4 acc[4][2];
#pragma unroll
    for (int i = 0; i < 4; ++i)
#pragma unroll
      for (int j = 0; j < 2; ++j) acc[i][j] = (f32x4){0.f, 0.f, 0.f, 0.f};

#pragma unroll
    for (int ksi = 0; ksi < 8; ++ksi) {
      const int ks = ksi ^ phase;
      bf16x8 a[4], b[2];
#pragma unroll
      for (int rf = 0; rf < 4; ++rf) a[rf] = *(const bf16x8*)&lds4[ks * 256 + rf * 64 + lane];
#pragma unroll
      for (int cf = 0; cf < 2; ++cf)
        b[cf] = *(const bf16x8*)(W1f + ((size_t)(ks * 64 + y * 16 + wid * 2 + cf)) * 512 + (size_t)lane * 8);
#pragma unroll
      for (int rf = 0; rf < 4; ++rf)
#pragma unroll
        for (int cf = 0; cf < 2; ++cf)
          acc[rf][cf] = __builtin_amdgcn_mfma_f32_16x16x32_bf16(a[rf], b[cf], acc[rf][cf], 0, 0, 0);
    }

    // epilogue: y0 -> qf f32 | y1,y2 -> kvb bf16 (dc0 0/256) | y3 -> sf f32
    bool bf16path;
    void* dstp_; int cstr_, dc0_, bcol0_;
    if (y == 0)      { bf16path = false; dstp_ = qf;  cstr_ = 256; dc0_ = 0;   bcol0_ = 0; }
    else if (y == 1) { bf16path = true;  dstp_ = kvb; cstr_ = 512; dc0_ = 0;   bcol0_ = 256; }
    else if (y == 2) { bf16path = true;  dstp_ = kvb; cstr_ = 512; dc0_ = 256; bcol0_ = 512; }
    else             { bf16path = false; dstp_ = sf;  cstr_ = 256; dc0_ = 0;   bcol0_ = 768; }
    if (!bf16path) {
      float* dst = (float*)dstp_;
      const int row0 = rt0 * 64 + fr0;
#pragma unroll
      for (int cf = 0; cf < 2; ++cf) {
        int c = wid * 32 + cf * 16 + fc0;
        float bv = bcat1[bcol0_ + c];
#pragma unroll
        for (int rf = 0; rf < 4; ++rf) {
#pragma unroll
          for (int j = 0; j < 4; ++j) {
            int r = row0 + rf * 16 + j;
            if (r < N_NODES) dst[(size_t)r * cstr_ + c] = acc[rf][cf][j] + bv;
          }
        }
      }
    } else {
      __syncthreads();
      unsigned short* cl = (unsigned short*)ldsraw;   // [64][72]
      unsigned short* dst = (unsigned short*)dstp_;
      for (int pass = 0; pass < 4; ++pass) {
        if ((wid >> 1) == pass) {
#pragma unroll
          for (int cf = 0; cf < 2; ++cf) {
            int c = (wid & 1) * 32 + cf * 16 + fc0;
            float bv = bcat1[bcol0_ + pass * 64 + c];
#pragma unroll
            for (int rf = 0; rf < 4; ++rf)
#pragma unroll
              for (int j = 0; j < 4; ++j)
                cl[(fr0 + rf * 16 + j) * 72 + c] = f2bf(acc[rf][cf][j] + bv);
          }
        }
        __syncthreads();
        {
          int row = tid >> 3, cc = (tid & 7) * 8;
          int gr = rt0 * 64 + row;
          if (gr < N_NODES)
            *(uint4*)&dst[(size_t)gr * cstr_ + dc0_ + pass * 64 + cc] = *(const uint4*)&cl[row * 72 + cc];
        }
        __syncthreads();
      }
    }
  }
}

// ---------------- node2 GEMM: LDS-free, barrier-free ----------------
__global__ __launch_bounds__(256)
void gemm_node2(const unsigned short* __restrict__ ha, const unsigned short* __restrict__ W2f,
                const float* __restrict__ bcat2, float* __restrict__ qkvs2) {
  const int tid = threadIdx.x;
  const int wid = tid >> 6, lane = tid & 63;
  const int wr = wid >> 1, wc = wid & 1;
  const int rt0 = blockIdx.x * 2;
  int rtA = rt0 + wr;
  if (rtA >= RT1) rtA = RT1 - 1;   // duplicate compute; stores guarded below

  f32x4 acc[4][4];
#pragma unroll
  for (int i = 0; i < 4; ++i)
#pragma unroll
    for (int j = 0; j < 4; ++j) acc[i][j] = (f32x4){0.f, 0.f, 0.f, 0.f};

#pragma unroll
  for (int ks = 0; ks < 8; ++ks) {
    bf16x8 a[4], b[4];
#pragma unroll
    for (int rf = 0; rf < 4; ++rf)
      a[rf] = *(const bf16x8*)(ha + (size_t)rtA * 16384 + (size_t)ks * 2048 + (size_t)(rf * 64 + lane) * 8);
#pragma unroll
    for (int cf = 0; cf < 4; ++cf)
      b[cf] = *(const bf16x8*)(W2f + ((size_t)(ks * 8 + wc * 4 + cf)) * 512 + (size_t)lane * 8);
#pragma unroll
    for (int rf = 0; rf < 4; ++rf)
#pragma unroll
      for (int cf = 0; cf < 4; ++cf)
        acc[rf][cf] = __builtin_amdgcn_mfma_f32_16x16x32_bf16(a[rf], b[cf], acc[rf][cf], 0, 0, 0);
  }

  const int row0 = (rt0 + wr) * 64 + ((lane >> 4) * 4);
  const int cb2 = wc * 64 + (lane & 15);
#pragma unroll
  for (int cf = 0; cf < 4; ++cf) {
    int c = cb2 + cf * 16;
    float bv = bcat2[c];
#pragma unroll
    for (int rf = 0; rf < 4; ++rf) {
#pragma unroll
      for (int j = 0; j < 4; ++j) {
        int r = row0 + rf * 16 + j;
        if (r < N_NODES) qkvs2[(size_t)r * 128 + c] = acc[rf][cf][j] + bv;
      }
    }
  }
}

// ---------------- attention layer 1: 2-edge unroll, dual online state ----------------
__global__ __launch_bounds__(64)
void attn1_kernel(const float* __restrict__ qf, const unsigned short* __restrict__ kvb,
                  const float* __restrict__ sf, const unsigned short* __restrict__ e1b,
                  const int* __restrict__ srcs, const int* __restrict__ rowptr,
                  unsigned short* __restrict__ ha) {
  const int n = blockIdx.x;
  const int lane = threadIdx.x;
  const int h = lane >> 3;
  const int c0 = (lane & 7) * 4;
  const int off = h * 32 + c0;
  const int beg = rowptr[n], end = rowptr[n + 1];
  const float4 q = *(const float4*)&qf[(size_t)n * 256 + off];
  float m0 = -INFINITY, d0 = 0.f, x0 = 0.f, x1 = 0.f, x2 = 0.f, x3 = 0.f;
  float m1 = -INFINITY, d1 = 0.f, y0 = 0.f, y1 = 0.f, y2 = 0.f, y3 = 0.f;
  int i = beg;
  for (; i + 1 < end; i += 2) {
    const int sA = srcs[i], sB = srcs[i + 1];
    ushort4 evA = *(const ushort4*)&e1b[(size_t)i * 256 + off];
    ushort4 kkA = *(const ushort4*)&kvb[(size_t)sA * 512 + off];
    ushort4 vvA = *(const ushort4*)&kvb[(size_t)sA * 512 + 256 + off];
    ushort4 evB = *(const ushort4*)&e1b[(size_t)(i + 1) * 256 + off];
    ushort4 kkB = *(const ushort4*)&kvb[(size_t)sB * 512 + off];
    ushort4 vvB = *(const ushort4*)&kvb[(size_t)sB * 512 + 256 + off];
    float eA0=bf2f(evA.x), eA1=bf2f(evA.y), eA2=bf2f(evA.z), eA3=bf2f(evA.w);
    float eB0=bf2f(evB.x), eB1=bf2f(evB.y), eB2=bf2f(evB.z), eB3=bf2f(evB.w);
    float pA = q.x*(bf2f(kkA.x)+eA0) + q.y*(bf2f(kkA.y)+eA1) + q.z*(bf2f(kkA.z)+eA2) + q.w*(bf2f(kkA.w)+eA3);
    float pB = q.x*(bf2f(kkB.x)+eB0) + q.y*(bf2f(kkB.y)+eB1) + q.z*(bf2f(kkB.z)+eB2) + q.w*(bf2f(kkB.w)+eB3);
    pA += __shfl_xor(pA, 1); pA += __shfl_xor(pA, 2); pA += __shfl_xor(pA, 4);
    pB += __shfl_xor(pB, 1); pB += __shfl_xor(pB, 2); pB += __shfl_xor(pB, 4);
    pA *= 0.17677669529663687f;
    pB *= 0.17677669529663687f;
    {
      const float mn = fmaxf(m0, pA);
      const float sc = __expf(m0 - mn), w = __expf(pA - mn);
      d0 = d0 * sc + w;
      x0 = x0 * sc + w * (bf2f(vvA.x) + eA0);
      x1 = x1 * sc + w * (bf2f(vvA.y) + eA1);
      x2 = x2 * sc + w * (bf2f(vvA.z) + eA2);
      x3 = x3 * sc + w * (bf2f(vvA.w) + eA3);
      m0 = mn;
    }
    {
      const float mn = fmaxf(m1, pB);
      const float sc = __expf(m1 - mn), w = __expf(pB - mn);
      d1 = d1 * sc + w;
      y0 = y0 * sc + w * (bf2f(vvB.x) + eB0);
      y1 = y1 * sc + w * (bf2f(vvB.y) + eB1);
      y2 = y2 * sc + w * (bf2f(vvB.z) + eB2);
      y3 = y3 * sc + w * (bf2f(vvB.w) + eB3);
      m1 = mn;
    }
  }
  if (i < end) {
    const int sA = srcs[i];
    ushort4 evA = *(const ushort4*)&e1b[(size_t)i * 256 + off];
    ushort4 kkA = *(const ushort4*)&kvb[(size_t)sA * 512 + off];
    ushort4 vvA = *(const ushort4*)&kvb[(size_t)sA * 512 + 256 + off];
    float eA0=bf2f(evA.x), eA1=bf2f(evA.y), eA2=bf2f(evA.z), eA3=bf2f(evA.w);
    float pA = q.x*(bf2f(kkA.x)+eA0) + q.y*(bf2f(kkA.y)+eA1) + q.z*(bf2f(kkA.z)+eA2) + q.w*(bf2f(kkA.w)+eA3);
    pA += __shfl_xor(pA, 1); pA += __shfl_xor(pA, 2); pA += __shfl_xor(pA, 4);
    pA *= 0.17677669529663687f;
    const float mn = fmaxf(m0, pA);
    const float sc = __expf(m0 - mn), w = __expf(pA - mn);
    d0 = d0 * sc + w;
    x0 = x0 * sc + w * (bf2f(vvA.x) + eA0);
    x1 = x1 * sc + w * (bf2f(vvA.y) + eA1);
    x2 = x2 * sc + w * (bf2f(vvA.z) + eA2);
    x3 = x3 * sc + w * (bf2f(vvA.w) + eA3);
    m0 = mn;
  }
  float den = d0, a0 = x0, a1 = x1, a2 = x2, a3 = x3;
  if (m1 != -INFINITY) {
    const float M = fmaxf(m0, m1);
    const float sA = __expf(m0 - M), sB = __expf(m1 - M);
    den = d0 * sA + d1 * sB;
    a0 = x0 * sA + y0 * sB; a1 = x1 * sA + y1 * sB;
    a2 = x2 * sA + y2 * sB; a3 = x3 * sA + y3 * sB;
  }
  const float inv = 1.f / (den + 1e-16f);
  const float4 sk = *(const float4*)&sf[(size_t)n * 256 + off];
  float o0 = fmaxf(a0 * inv + sk.x, 0.f);
  float o1 = fmaxf(a1 * inv + sk.y, 0.f);
  float o2 = fmaxf(a2 * inv + sk.z, 0.f);
  float o3 = fmaxf(a3 * inv + sk.w, 0.f);
  int rt = n >> 6, rf = (n >> 4) & 3, ir = n & 15;
  int kg = (lane & 7) >> 1, jj = 4 * (lane & 1);
  ushort4 w4;
  w4.x = f2bf(o0); w4.y = f2bf(o1); w4.z = f2bf(o2); w4.w = f2bf(o3);
  *(ushort4*)&ha[(size_t)rt * 16384 + h * 2048 + rf * 512 + (ir + 16 * kg) * 8 + jj] = w4;
}

// ---------------- attention layer 2: 2-edge unroll ----------------
__global__ __launch_bounds__(64)
void attn2_kernel(const float* __restrict__ qkvs2, const unsigned short* __restrict__ e2b,
                  const int* __restrict__ srcs, const int* __restrict__ rowptr,
                  float* __restrict__ outp) {
  const int n = blockIdx.x;
  const int tid = threadIdx.x;
  const int c = tid & 31;
  const int beg = rowptr[n], end = rowptr[n + 1];
  const float qv = qkvs2[(size_t)n * 128 + c];
  float m0 = -INFINITY, d0 = 0.f, x0 = 0.f;
  float m1 = -INFINITY, d1 = 0.f, y0 = 0.f;
  int i = beg;
  for (; i + 1 < end; i += 2) {
    const int sA = srcs[i], sB = srcs[i + 1];
    const float eA = bf2f(e2b[(size_t)i * 32 + c]);
    const float eB = bf2f(e2b[(size_t)(i + 1) * 32 + c]);
    float pA = qv * (qkvs2[(size_t)sA * 128 + 32 + c] + eA);
    float pB = qv * (qkvs2[(size_t)sB * 128 + 32 + c] + eB);
    const float vA = qkvs2[(size_t)sA * 128 + 64 + c] + eA;
    const float vB = qkvs2[(size_t)sB * 128 + 64 + c] + eB;
#pragma unroll
    for (int off = 16; off; off >>= 1) pA += __shfl_xor(pA, off);
#pragma unroll
    for (int off = 16; off; off >>= 1) pB += __shfl_xor(pB, off);
    pA *= 0.17677669529663687f;
    pB *= 0.17677669529663687f;
    {
      const float mn = fmaxf(m0, pA);
      const float sc = __expf(m0 - mn), w = __expf(pA - mn);
      d0 = d0 * sc + w; x0 = x0 * sc + w * vA; m0 = mn;
    }
    {
      const float mn = fmaxf(m1, pB);
      const float sc = __expf(m1 - mn), w = __expf(pB - mn);
      d1 = d1 * sc + w; y0 = y0 * sc + w * vB; m1 = mn;
    }
  }
  if (i < end) {
    const int sA = srcs[i];
    const float eA = bf2f(e2b[(size_t)i * 32 + c]);
    float pA = qv * (qkvs2[(size_t)sA * 128 + 32 + c] + eA);
    const float vA = qkvs2[(size_t)sA * 128 + 64 + c] + eA;
#pragma unroll
    for (int off = 16; off; off >>= 1) pA += __shfl_xor(pA, off);
    pA *= 0.17677669529663687f;
    const float mn = fmaxf(m0, pA);
    const float sc = __expf(m0 - mn), w = __expf(pA - mn);
    d0 = d0 * sc + w; x0 = x0 * sc + w * vA; m0 = mn;
  }
  float den = d0, acc = x0;
  if (m1 != -INFINITY) {
    const float M = fmaxf(m0, m1);
    const float sA = __expf(m0 - M), sB = __expf(m1 - M);
    den = d0 * sA + d1 * sB;
    acc = x0 * sA + y0 * sB;
  }
  if (tid < 32) {
    float o = acc / (den + 1e-16f) + qkvs2[(size_t)n * 128 + 96 + c];
    outp[(size_t)n * 32 + c] = fmaxf(o, 0.f);
  }
}

// ---------------- launcher ----------------
extern "C" void kernel_launch(void* const* d_in, const int* in_sizes, int n_in,
                              void* d_out, int out_size, void* d_ws, size_t ws_size,
                              hipStream_t stream) {
  const float* x   = (const float*)d_in[0];
  const float* lu  = (const float*)d_in[1];
  const int*   ei  = (const int*)d_in[2];
  const float* tt  = (const float*)d_in[3];
  const float* msg = (const float*)d_in[4];
  const float* tw  = (const float*)d_in[5];
  const float* tb  = (const float*)d_in[6];
  const float* Wq1 = (const float*)d_in[7];  const float* bq1 = (const float*)d_in[8];
  const float* Wk1 = (const float*)d_in[9];  const float* bk1 = (const float*)d_in[10];
  const float* Wv1 = (const float*)d_in[11]; const float* bv1 = (const float*)d_in[12];
  const float* We1 = (const float*)d_in[13];
  const float* Ws1 = (const float*)d_in[14]; const float* bs1 = (const float*)d_in[15];
  const float* Wq2 = (const float*)d_in[16]; const float* bq2 = (const float*)d_in[17];
  const float* Wk2 = (const float*)d_in[18]; const float* bk2 = (const float*)d_in[19];
  const float* Wv2 = (const float*)d_in[20]; const float* bv2 = (const float*)d_in[21];
  const float* We2 = (const float*)d_in[22];
  const float* Ws2 = (const float*)d_in[23]; const float* bs2 = (const float*)d_in[24];

  const int* srcp = ei;
  const int* dstp = ei + N_EDGES;

  char* p = (char*)d_ws;
  auto alloc = [&](size_t bytes) -> char* {
    char* r = p;
    p += (bytes + 255) & ~(size_t)255;
    return r;
  };
  int*   deg     = (int*)alloc((size_t)N_NODES * 4);
  int*   fill    = (int*)alloc((size_t)N_NODES * 4);
  int*   rowptr  = (int*)alloc((size_t)(N_NODES + 1) * 4);
  int*   sortpos = (int*)alloc((size_t)N_EDGES * 4);
  int*   srcs    = (int*)alloc((size_t)N_EDGES * 4);
  float* rel     = (float*)alloc((size_t)N_EDGES * 4);
  unsigned short* xa   = (unsigned short*)alloc((size_t)RT1 * 32768);
  unsigned short* W1f  = (unsigned short*)alloc((size_t)8 * 64 * 1024);
  unsigned short* We1f = (unsigned short*)alloc((size_t)8 * 16 * 1024);
  unsigned short* W2f  = (unsigned short*)alloc((size_t)8 * 8 * 1024);
  unsigned short* We2f = (unsigned short*)alloc((size_t)8 * 4 * 1024);
  float* bcat1  = (float*)alloc(1024 * 4);
  float* bcat2  = (float*)alloc(128 * 4);
  float* qf     = (float*)alloc((size_t)N_NODES * 256 * 4);
  unsigned short* kvb = (unsigned short*)alloc((size_t)N_NODES * 512 * 2);
  float* sf     = (float*)alloc((size_t)N_NODES * 256 * 4);
  unsigned short* e1b = (unsigned short*)alloc((size_t)N_EDGES * 256 * 2);   // 82 MB
  unsigned short* ha  = (unsigned short*)alloc((size_t)RT1 * 32768);
  float* qkvs2  = (float*)alloc((size_t)N_NODES * 128 * 4);
  unsigned short* e2b = (unsigned short*)alloc((size_t)N_EDGES * 32 * 2);
  float* outp   = (float*)d_out;

  hipMemsetAsync(deg, 0, (size_t)N_NODES * 4, stream);
  hipMemsetAsync(fill, 0, (size_t)N_NODES * 4, stream);
  hipMemsetAsync(ha + (size_t)(RT1 - 1) * 16384, 0, 32768, stream);  // zero pad rows 10000-10047

  prep1_kernel<<<625, 256, 0, stream>>>(lu, srcp, dstp, tt, rel, deg, N_EDGES);
  scan_kernel<<<1, 1024, 0, stream>>>(deg, rowptr, N_NODES);
  scatter_kernel<<<625, 256, 0, stream>>>(srcp, dstp, rowptr, fill, sortpos, srcs, N_EDGES);

  conv_all_kernel<<<ceildiv(CONVX_T + 369792, 256), 256, 0, stream>>>(
      x, xa, Wq1, Wk1, Wv1, Ws1, We1, Wq2, Wk2, Wv2, Ws2, We2,
      bq1, bk1, bv1, bs1, bq2, bk2, bv2, bs2,
      W1f, We1f, W2f, We2f, bcat1, bcat2);

  // merged: 2500 edge blocks + 628 node1 blocks, 512 threads, low-acc waves
  big_gemm<<<RTE + RT1 * 4, 512, 0, stream>>>(
      xa, W1f, bcat1, qf, kvb, sf, We1f, We2f, e1b, e2b,
      rel, tw, tb, msg, sortpos);

  attn1_kernel<<<N_NODES, 64, 0, stream>>>(qf, kvb, sf, e1b, srcs, rowptr, ha);
  gemm_node2<<<ceildiv(RT1, 2), 256, 0, stream>>>(ha, W2f, bcat2, qkvs2);
  attn2_kernel<<<N_NODES, 64, 0, stream>>>(qkvs2, e2b, srcs, rowptr, outp);
}

// Round 11
// 176.684 us; speedup vs baseline: 1.1278x; 1.0750x over previous
//
#include <hip/hip_runtime.h>
#include <math.h>

#define N_NODES 10000
#define N_EDGES 160000
#define RT1 157      // ceil(10000/64)
#define RTE 2500     // 160000/64
#define CONVX_T (RT1 * 64 * 32)   // 321536

static inline int ceildiv(int a, int b) { return (a + b - 1) / b; }

typedef float f32x4 __attribute__((ext_vector_type(4)));
typedef short bf16x8 __attribute__((ext_vector_type(8)));

__device__ __forceinline__ unsigned short f2bf(float f) {
  unsigned int u = __builtin_bit_cast(unsigned int, f);
  u += 0x7FFFu + ((u >> 16) & 1u);   // RNE
  return (unsigned short)(u >> 16);
}
__device__ __forceinline__ float bf2f(unsigned short h) {
  unsigned int u = ((unsigned int)h) << 16;
  return __builtin_bit_cast(float, u);
}

// ---------------- prep: rel + degree count fused ----------------
__global__ void prep1_kernel(const float* __restrict__ lu, const int* __restrict__ srcp,
                             const int* __restrict__ dstp, const float* __restrict__ tt,
                             float* __restrict__ rel, int* __restrict__ deg, int E) {
  for (int i = blockIdx.x * blockDim.x + threadIdx.x; i < E; i += gridDim.x * blockDim.x) {
    rel[i] = lu[srcp[i]] - tt[i];
    atomicAdd(&deg[dstp[i]], 1);
  }
}

__global__ void scan_kernel(const int* __restrict__ deg, int* __restrict__ rowptr, int n) {
  __shared__ int part[1024];
  const int tid = threadIdx.x;
  const int CHK = 10;
  int base = tid * CHK;
  int loc[CHK];
  int s = 0;
#pragma unroll
  for (int j = 0; j < CHK; ++j) {
    int idx = base + j;
    int v = (idx < n) ? deg[idx] : 0;
    loc[j] = s; s += v;
  }
  part[tid] = s;
  __syncthreads();
  for (int off = 1; off < 1024; off <<= 1) {
    int y = (tid >= off) ? part[tid - off] : 0;
    __syncthreads();
    part[tid] += y;
    __syncthreads();
  }
  int pre = tid ? part[tid - 1] : 0;
#pragma unroll
  for (int j = 0; j < CHK; ++j) {
    int idx = base + j;
    if (idx < n) rowptr[idx] = pre + loc[j];
  }
  if (tid == 1023) rowptr[n] = part[1023];
}

__global__ void scatter_kernel(const int* __restrict__ srcp, const int* __restrict__ dstp,
                               const int* __restrict__ rowptr, int* __restrict__ fill,
                               int* __restrict__ sortpos, int* __restrict__ srcs, int E) {
  for (int e = blockIdx.x * blockDim.x + threadIdx.x; e < E; e += gridDim.x * blockDim.x) {
    int d = dstp[e];
    int pos = atomicAdd(&fill[d], 1);
    int slot = rowptr[d] + pos;
    sortpos[e] = slot;
    srcs[slot] = srcp[e];
  }
}

// ---------------- all format conversions in ONE launch ----------------
// A frag layout (ushorts): addr(i,k)= rt*16384 + ks*2048 + rf*512 + (ir+16*kg)*8 + j
// B frag layout: addr(k,c) = (ks*NFtot + (c>>4))*512 + ((c&15)+16*kg)*8 + j
__device__ __forceinline__ void wstore(const float* __restrict__ W, unsigned short* __restrict__ out,
                                       int Nin, int n_off, int NFtot, int k, int c) {
  int gc = n_off + c;
  int ks=k>>5, kg=(k>>3)&3, j=k&7, nf=gc>>4, ic=gc&15;
  out[(size_t)(ks*NFtot+nf)*512 + (ic+16*kg)*8 + j] = f2bf(W[(size_t)k*Nin + c]);
}

__global__ void conv_all_kernel(const float* __restrict__ x, unsigned short* __restrict__ xa,
                                const float* Wq1, const float* Wk1, const float* Wv1, const float* Ws1,
                                const float* We1, const float* Wq2, const float* Wk2, const float* Wv2,
                                const float* Ws2, const float* We2,
                                const float* bq1, const float* bk1, const float* bv1, const float* bs1,
                                const float* bq2, const float* bk2, const float* bv2, const float* bs2,
                                unsigned short* W1f, unsigned short* We1f, unsigned short* W2f,
                                unsigned short* We2f, float* bcat1, float* bcat2) {
  int t0 = blockIdx.x * blockDim.x + threadIdx.x;
  if (t0 < CONVX_T) {
    int i = t0 >> 5, k8 = t0 & 31;
    union { uint4 q; unsigned short s[8]; } u;
    if (i < N_NODES) {
      const float4* px = (const float4*)(x + (size_t)i * 256 + k8 * 8);
      float4 f0 = px[0], f1 = px[1];
      u.s[0]=f2bf(f0.x); u.s[1]=f2bf(f0.y); u.s[2]=f2bf(f0.z); u.s[3]=f2bf(f0.w);
      u.s[4]=f2bf(f1.x); u.s[5]=f2bf(f1.y); u.s[6]=f2bf(f1.z); u.s[7]=f2bf(f1.w);
    } else {
      u.q = make_uint4(0,0,0,0);
    }
    int rt=i>>6, rf=(i>>4)&3, ir=i&15, ks=k8>>2, kg=k8&3;
    *(uint4*)&xa[(size_t)rt*16384 + ks*2048 + rf*512 + (ir+16*kg)*8] = u.q;
    return;
  }
  int t = t0 - CONVX_T;
  if (t < 262144) {               // W1f: 4 x 256x256
    int w = t >> 16, r = t & 65535, k = r >> 8, c = r & 255;
    const float* W = (w == 0) ? Wq1 : (w == 1) ? Wk1 : (w == 2) ? Wv1 : Ws1;
    wstore(W, W1f, 256, w * 256, 64, k, c);
  } else if (t < 327680) {        // We1f: 256x256
    int r = t - 262144, k = r >> 8, c = r & 255;
    wstore(We1, We1f, 256, 0, 16, k, c);
  } else if (t < 360448) {        // W2f: 4 x 256x32
    int r = t - 327680, w = r >> 13, r2 = r & 8191, k = r2 >> 5, c = r2 & 31;
    const float* W = (w == 0) ? Wq2 : (w == 1) ? Wk2 : (w == 2) ? Wv2 : Ws2;
    wstore(W, W2f, 32, w * 32, 8, k, c);
  } else if (t < 368640) {        // We2f: 256x32 (cols 32-63 pre-zeroed by memset)
    int r = t - 360448, k = r >> 5, c = r & 31;
    wstore(We2, We2f, 32, 0, 4, k, c);
  } else if (t < 369792) {        // biases
    int r = t - 368640;
    if (r < 1024) {
      const float* b = (r < 256) ? bq1 : (r < 512) ? bk1 : (r < 768) ? bv1 : bs1;
      bcat1[r] = b[r & 255];
    } else {
      int r2 = r - 1024;
      const float* b = (r2 < 32) ? bq2 : (r2 < 64) ? bk2 : (r2 < 96) ? bv2 : bs2;
      bcat2[r2] = b[r2 & 31];
    }
  }
}

// ---------------- BIG merged GEMM: 512 threads, 8 waves, 64x32 per wave ----------------
// R11: explicit 1-step software pipeline (aN/bN regs loaded before current MFMAs) +
// __launch_bounds__(512,4) so the compiler has ~128 VGPRs for load buffering
// (R10's 52-VGPR compile serialized every B-load behind its MFMA).
__global__ __launch_bounds__(512, 4)
void big_gemm(const unsigned short* __restrict__ xa, const unsigned short* __restrict__ W1f,
              const float* __restrict__ bcat1, float* __restrict__ qf,
              unsigned short* __restrict__ kvb, float* __restrict__ sf,
              const unsigned short* __restrict__ We1f, const unsigned short* __restrict__ We2f,
              unsigned short* __restrict__ e1b, unsigned short* __restrict__ e2b,
              const float* __restrict__ rel, const float* __restrict__ tw,
              const float* __restrict__ tb, const float* __restrict__ msg,
              const int* __restrict__ sortpos) {
  __shared__ char ldsraw[32768];        // A tile (8 K-steps x 4KB); reused by epilogue
  uint4* lds4 = (uint4*)ldsraw;
  const int tid = threadIdx.x;
  const int wid = tid >> 6, lane = tid & 63;
  const int bx = blockIdx.x;
  const int fr0 = (lane >> 4) * 4;
  const int fc0 = lane & 15;

  if (bx < RTE) {
    // ================= edge path =================
    const int rt0 = bx;
    const int phase = bx & 7;
    // prologue: 2048 A-chunks over 512 threads (2 cos + 2 msg each)
    {
      const int rem = tid & 255;
      const int ksh = tid >> 8;                // 0 or 1
      const int arf = rem >> 6, ar2 = rem & 63, air = ar2 & 15, akg = ar2 >> 4;
      const int aedge = rt0 * 64 + arf * 16 + air;
      float rl = rel[aedge];
#pragma unroll
      for (int s = 0; s < 2; ++s) {
        int ks = ksh + s * 2;                  // cos K-steps 0..3
        int k8 = ks * 4 + akg;
        const float4* twp = (const float4*)(tw + k8 * 8);
        const float4* tbp = (const float4*)(tb + k8 * 8);
        float4 w0 = twp[0], w1 = twp[1], b0 = tbp[0], b1 = tbp[1];
        union { uint4 q; unsigned short us[8]; } u;
        u.us[0]=f2bf(__cosf(rl*w0.x+b0.x)); u.us[1]=f2bf(__cosf(rl*w0.y+b0.y));
        u.us[2]=f2bf(__cosf(rl*w0.z+b0.z)); u.us[3]=f2bf(__cosf(rl*w0.w+b0.w));
        u.us[4]=f2bf(__cosf(rl*w1.x+b1.x)); u.us[5]=f2bf(__cosf(rl*w1.y+b1.y));
        u.us[6]=f2bf(__cosf(rl*w1.z+b1.z)); u.us[7]=f2bf(__cosf(rl*w1.w+b1.w));
        lds4[ks * 256 + rem] = u.q;
      }
#pragma unroll
      for (int s = 0; s < 2; ++s) {
        int ks = 4 + ksh + s * 2;              // msg K-steps 4..7
        int k8 = ks * 4 + akg;                 // 16..31
        const float4* pm = (const float4*)(msg + (size_t)aedge * 128 + (size_t)(k8 - 16) * 8);
        float4 f0 = pm[0], f1 = pm[1];
        union { uint4 q; unsigned short us[8]; } u;
        u.us[0]=f2bf(f0.x); u.us[1]=f2bf(f0.y); u.us[2]=f2bf(f0.z); u.us[3]=f2bf(f0.w);
        u.us[4]=f2bf(f1.x); u.us[5]=f2bf(f1.y); u.us[6]=f2bf(f1.z); u.us[7]=f2bf(f1.w);
        lds4[ks * 256 + rem] = u.q;
      }
    }
    __syncthreads();

    f32x4 acc[4][2];
    f32x4 acc2[4];
#pragma unroll
    for (int i = 0; i < 4; ++i) {
      acc2[i] = (f32x4){0.f, 0.f, 0.f, 0.f};
#pragma unroll
      for (int j = 0; j < 2; ++j) acc[i][j] = (f32x4){0.f, 0.f, 0.f, 0.f};
    }

    // software pipeline: aN/bN/b2N hold NEXT step's operands
    bf16x8 aN0, aN1, aN2, aN3, bN0, bN1, b2N;
    {
      const int ks = phase;
      aN0 = *(const bf16x8*)&lds4[ks * 256 + 0 * 64 + lane];
      aN1 = *(const bf16x8*)&lds4[ks * 256 + 1 * 64 + lane];
      aN2 = *(const bf16x8*)&lds4[ks * 256 + 2 * 64 + lane];
      aN3 = *(const bf16x8*)&lds4[ks * 256 + 3 * 64 + lane];
      bN0 = *(const bf16x8*)(We1f + ((size_t)(ks * 16 + wid * 2 + 0)) * 512 + (size_t)lane * 8);
      bN1 = *(const bf16x8*)(We1f + ((size_t)(ks * 16 + wid * 2 + 1)) * 512 + (size_t)lane * 8);
      b2N = 0;
      if (wid < 2) b2N = *(const bf16x8*)(We2f + ((size_t)(ks * 4 + wid)) * 512 + (size_t)lane * 8);
    }
#pragma unroll
    for (int ksi = 0; ksi < 8; ++ksi) {
      bf16x8 aC0 = aN0, aC1 = aN1, aC2 = aN2, aC3 = aN3;
      bf16x8 bC0 = bN0, bC1 = bN1, b2C = b2N;
      if (ksi < 7) {
        const int ks2 = (ksi + 1) ^ phase;
        aN0 = *(const bf16x8*)&lds4[ks2 * 256 + 0 * 64 + lane];
        aN1 = *(const bf16x8*)&lds4[ks2 * 256 + 1 * 64 + lane];
        aN2 = *(const bf16x8*)&lds4[ks2 * 256 + 2 * 64 + lane];
        aN3 = *(const bf16x8*)&lds4[ks2 * 256 + 3 * 64 + lane];
        bN0 = *(const bf16x8*)(We1f + ((size_t)(ks2 * 16 + wid * 2 + 0)) * 512 + (size_t)lane * 8);
        bN1 = *(const bf16x8*)(We1f + ((size_t)(ks2 * 16 + wid * 2 + 1)) * 512 + (size_t)lane * 8);
        if (wid < 2) b2N = *(const bf16x8*)(We2f + ((size_t)(ks2 * 4 + wid)) * 512 + (size_t)lane * 8);
      }
      acc[0][0] = __builtin_amdgcn_mfma_f32_16x16x32_bf16(aC0, bC0, acc[0][0], 0, 0, 0);
      acc[1][0] = __builtin_amdgcn_mfma_f32_16x16x32_bf16(aC1, bC0, acc[1][0], 0, 0, 0);
      acc[2][0] = __builtin_amdgcn_mfma_f32_16x16x32_bf16(aC2, bC0, acc[2][0], 0, 0, 0);
      acc[3][0] = __builtin_amdgcn_mfma_f32_16x16x32_bf16(aC3, bC0, acc[3][0], 0, 0, 0);
      acc[0][1] = __builtin_amdgcn_mfma_f32_16x16x32_bf16(aC0, bC1, acc[0][1], 0, 0, 0);
      acc[1][1] = __builtin_amdgcn_mfma_f32_16x16x32_bf16(aC1, bC1, acc[1][1], 0, 0, 0);
      acc[2][1] = __builtin_amdgcn_mfma_f32_16x16x32_bf16(aC2, bC1, acc[2][1], 0, 0, 0);
      acc[3][1] = __builtin_amdgcn_mfma_f32_16x16x32_bf16(aC3, bC1, acc[3][1], 0, 0, 0);
      if (wid < 2) {
        acc2[0] = __builtin_amdgcn_mfma_f32_16x16x32_bf16(aC0, b2C, acc2[0], 0, 0, 0);
        acc2[1] = __builtin_amdgcn_mfma_f32_16x16x32_bf16(aC1, b2C, acc2[1], 0, 0, 0);
        acc2[2] = __builtin_amdgcn_mfma_f32_16x16x32_bf16(aC2, b2C, acc2[2], 0, 0, 0);
        acc2[3] = __builtin_amdgcn_mfma_f32_16x16x32_bf16(aC3, b2C, acc2[3], 0, 0, 0);
      }
    }

    // epilogue: scatter e1 (64x256) + e2 (64x32) rows to sorted slots
    __syncthreads();
    unsigned short* cl  = (unsigned short*)ldsraw;            // [64][72]
    unsigned short* cl2 = (unsigned short*)(ldsraw + 9216);   // [64][40]
    int* spos = (int*)(ldsraw + 14336);                       // [64]
    if (tid < 64) spos[tid] = sortpos[rt0 * 64 + tid];
    if (wid < 2) {
#pragma unroll
      for (int rf = 0; rf < 4; ++rf)
#pragma unroll
        for (int j = 0; j < 4; ++j)
          cl2[(fr0 + rf * 16 + j) * 40 + wid * 16 + fc0] = f2bf(acc2[rf][j]);
    }
    for (int pass = 0; pass < 4; ++pass) {
      if ((wid >> 1) == pass) {                // waves 2p,2p+1 own cols [p*64, p*64+64)
#pragma unroll
        for (int cf = 0; cf < 2; ++cf) {
          int c = (wid & 1) * 32 + cf * 16 + fc0;
#pragma unroll
          for (int rf = 0; rf < 4; ++rf)
#pragma unroll
            for (int j = 0; j < 4; ++j)
              cl[(fr0 + rf * 16 + j) * 72 + c] = f2bf(acc[rf][cf][j]);
        }
      }
      __syncthreads();
      {
        int row = tid >> 3, cc = (tid & 7) * 8;   // 512 chunks exactly
        int gr = spos[row];
        *(uint4*)&e1b[(size_t)gr * 256 + pass * 64 + cc] = *(const uint4*)&cl[row * 72 + cc];
      }
      __syncthreads();
    }
    if (tid < 256) {
      int row = tid >> 2, cc = (tid & 3) * 8;
      int gr = spos[row];
      *(uint4*)&e2b[(size_t)gr * 32 + cc] = *(const uint4*)&cl2[row * 40 + cc];
    }
  } else {
    // ================= node1 path =================
    const int idx = bx - RTE;
    const int rt0 = idx % RT1;
    const int y = idx / RT1;                   // 0..3: q | k | v | s
    const int phase = rt0 & 7;

    // prologue: all 8 A K-steps (32KB linear copy); ONE barrier
#pragma unroll
    for (int s = 0; s < 4; ++s)
      lds4[tid + s * 512] = *(const uint4*)(xa + (size_t)rt0 * 16384 + (size_t)(tid + s * 512) * 8);
    __syncthreads();

    f32x4 acc[4][2];
#pragma unroll
    for (int i = 0; i < 4; ++i)
#pragma unroll
      for (int j = 0; j < 2; ++j) acc[i][j] = (f32x4){0.f, 0.f, 0.f, 0.f};

    bf16x8 aN0, aN1, aN2, aN3, bN0, bN1;
    {
      const int ks = phase;
      aN0 = *(const bf16x8*)&lds4[ks * 256 + 0 * 64 + lane];
      aN1 = *(const bf16x8*)&lds4[ks * 256 + 1 * 64 + lane];
      aN2 = *(const bf16x8*)&lds4[ks * 256 + 2 * 64 + lane];
      aN3 = *(const bf16x8*)&lds4[ks * 256 + 3 * 64 + lane];
      bN0 = *(const bf16x8*)(W1f + ((size_t)(ks * 64 + y * 16 + wid * 2 + 0)) * 512 + (size_t)lane * 8);
      bN1 = *(const bf16x8*)(W1f + ((size_t)(ks * 64 + y * 16 + wid * 2 + 1)) * 512 + (size_t)lane * 8);
    }
#pragma unroll
    for (int ksi = 0; ksi < 8; ++ksi) {
      bf16x8 aC0 = aN0, aC1 = aN1, aC2 = aN2, aC3 = aN3;
      bf16x8 bC0 = bN0, bC1 = bN1;
      if (ksi < 7) {
        const int ks2 = (ksi + 1) ^ phase;
        aN0 = *(const bf16x8*)&lds4[ks2 * 256 + 0 * 64 + lane];
        aN1 = *(const bf16x8*)&lds4[ks2 * 256 + 1 * 64 + lane];
        aN2 = *(const bf16x8*)&lds4[ks2 * 256 + 2 * 64 + lane];
        aN3 = *(const bf16x8*)&lds4[ks2 * 256 + 3 * 64 + lane];
        bN0 = *(const bf16x8*)(W1f + ((size_t)(ks2 * 64 + y * 16 + wid * 2 + 0)) * 512 + (size_t)lane * 8);
        bN1 = *(const bf16x8*)(W1f + ((size_t)(ks2 * 64 + y * 16 + wid * 2 + 1)) * 512 + (size_t)lane * 8);
      }
      acc[0][0] = __builtin_amdgcn_mfma_f32_16x16x32_bf16(aC0, bC0, acc[0][0], 0, 0, 0);
      acc[1][0] = __builtin_amdgcn_mfma_f32_16x16x32_bf16(aC1, bC0, acc[1][0], 0, 0, 0);
      acc[2][0] = __builtin_amdgcn_mfma_f32_16x16x32_bf16(aC2, bC0, acc[2][0], 0, 0, 0);
      acc[3][0] = __builtin_amdgcn_mfma_f32_16x16x32_bf16(aC3, bC0, acc[3][0], 0, 0, 0);
      acc[0][1] = __builtin_amdgcn_mfma_f32_16x16x32_bf16(aC0, bC1, acc[0][1], 0, 0, 0);
      acc[1][1] = __builtin_amdgcn_mfma_f32_16x16x32_bf16(aC1, bC1, acc[1][1], 0, 0, 0);
      acc[2][1] = __builtin_amdgcn_mfma_f32_16x16x32_bf16(aC2, bC1, acc[2][1], 0, 0, 0);
      acc[3][1] = __builtin_amdgcn_mfma_f32_16x16x32_bf16(aC3, bC1, acc[3][1], 0, 0, 0);
    }

    // epilogue: y0 -> qf f32 | y1,y2 -> kvb bf16 (dc0 0/256) | y3 -> sf f32
    bool bf16path;
    void* dstp_; int cstr_, dc0_, bcol0_;
    if (y == 0)      { bf16path = false; dstp_ = qf;  cstr_ = 256; dc0_ = 0;   bcol0_ = 0; }
    else if (y == 1) { bf16path = true;  dstp_ = kvb; cstr_ = 512; dc0_ = 0;   bcol0_ = 256; }
    else if (y == 2) { bf16path = true;  dstp_ = kvb; cstr_ = 512; dc0_ = 256; bcol0_ = 512; }
    else             { bf16path = false; dstp_ = sf;  cstr_ = 256; dc0_ = 0;   bcol0_ = 768; }
    if (!bf16path) {
      float* dst = (float*)dstp_;
      const int row0 = rt0 * 64 + fr0;
#pragma unroll
      for (int cf = 0; cf < 2; ++cf) {
        int c = wid * 32 + cf * 16 + fc0;
        float bv = bcat1[bcol0_ + c];
#pragma unroll
        for (int rf = 0; rf < 4; ++rf) {
#pragma unroll
          for (int j = 0; j < 4; ++j) {
            int r = row0 + rf * 16 + j;
            if (r < N_NODES) dst[(size_t)r * cstr_ + c] = acc[rf][cf][j] + bv;
          }
        }
      }
    } else {
      __syncthreads();
      unsigned short* cl = (unsigned short*)ldsraw;   // [64][72]
      unsigned short* dst = (unsigned short*)dstp_;
      for (int pass = 0; pass < 4; ++pass) {
        if ((wid >> 1) == pass) {
#pragma unroll
          for (int cf = 0; cf < 2; ++cf) {
            int c = (wid & 1) * 32 + cf * 16 + fc0;
            float bv = bcat1[bcol0_ + pass * 64 + c];
#pragma unroll
            for (int rf = 0; rf < 4; ++rf)
#pragma unroll
              for (int j = 0; j < 4; ++j)
                cl[(fr0 + rf * 16 + j) * 72 + c] = f2bf(acc[rf][cf][j] + bv);
          }
        }
        __syncthreads();
        {
          int row = tid >> 3, cc = (tid & 7) * 8;
          int gr = rt0 * 64 + row;
          if (gr < N_NODES)
            *(uint4*)&dst[(size_t)gr * cstr_ + dc0_ + pass * 64 + cc] = *(const uint4*)&cl[row * 72 + cc];
        }
        __syncthreads();
      }
    }
  }
}

// ---------------- node2 GEMM: LDS-free, barrier-free ----------------
__global__ __launch_bounds__(256)
void gemm_node2(const unsigned short* __restrict__ ha, const unsigned short* __restrict__ W2f,
                const float* __restrict__ bcat2, float* __restrict__ qkvs2) {
  const int tid = threadIdx.x;
  const int wid = tid >> 6, lane = tid & 63;
  const int wr = wid >> 1, wc = wid & 1;
  const int rt0 = blockIdx.x * 2;
  int rtA = rt0 + wr;
  if (rtA >= RT1) rtA = RT1 - 1;

  f32x4 acc[4][4];
#pragma unroll
  for (int i = 0; i < 4; ++i)
#pragma unroll
    for (int j = 0; j < 4; ++j) acc[i][j] = (f32x4){0.f, 0.f, 0.f, 0.f};

#pragma unroll
  for (int ks = 0; ks < 8; ++ks) {
    bf16x8 a[4], b[4];
#pragma unroll
    for (int rf = 0; rf < 4; ++rf)
      a[rf] = *(const bf16x8*)(ha + (size_t)rtA * 16384 + (size_t)ks * 2048 + (size_t)(rf * 64 + lane) * 8);
#pragma unroll
    for (int cf = 0; cf < 4; ++cf)
      b[cf] = *(const bf16x8*)(W2f + ((size_t)(ks * 8 + wc * 4 + cf)) * 512 + (size_t)lane * 8);
#pragma unroll
    for (int rf = 0; rf < 4; ++rf)
#pragma unroll
      for (int cf = 0; cf < 4; ++cf)
        acc[rf][cf] = __builtin_amdgcn_mfma_f32_16x16x32_bf16(a[rf], b[cf], acc[rf][cf], 0, 0, 0);
  }

  const int row0 = (rt0 + wr) * 64 + ((lane >> 4) * 4);
  const int cb2 = wc * 64 + (lane & 15);
#pragma unroll
  for (int cf = 0; cf < 4; ++cf) {
    int c = cb2 + cf * 16;
    float bv = bcat2[c];
#pragma unroll
    for (int rf = 0; rf < 4; ++rf) {
#pragma unroll
      for (int j = 0; j < 4; ++j) {
        int r = row0 + rf * 16 + j;
        if (r < N_NODES) qkvs2[(size_t)r * 128 + c] = acc[rf][cf][j] + bv;
      }
    }
  }
}

// ---------------- attention layer 1: 4 independent online states ----------------
__global__ __launch_bounds__(64)
void attn1_kernel(const float* __restrict__ qf, const unsigned short* __restrict__ kvb,
                  const float* __restrict__ sf, const unsigned short* __restrict__ e1b,
                  const int* __restrict__ srcs, const int* __restrict__ rowptr,
                  unsigned short* __restrict__ ha) {
  const int n = blockIdx.x;
  const int lane = threadIdx.x;
  const int h = lane >> 3;
  const int c0 = (lane & 7) * 4;
  const int off = h * 32 + c0;
  const int beg = rowptr[n], end = rowptr[n + 1];
  const float4 q = *(const float4*)&qf[(size_t)n * 256 + off];

  float m0=-INFINITY,d0=0,x00=0,x01=0,x02=0,x03=0;
  float m1=-INFINITY,d1=0,x10=0,x11=0,x12=0,x13=0;
  float m2=-INFINITY,d2=0,x20=0,x21=0,x22=0,x23=0;
  float m3=-INFINITY,d3=0,x30=0,x31=0,x32=0,x33=0;

  auto step = [&](int i, float& m, float& d, float& a0, float& a1, float& a2, float& a3) {
    const int s = srcs[i];
    ushort4 ev = *(const ushort4*)&e1b[(size_t)i * 256 + off];
    ushort4 kk = *(const ushort4*)&kvb[(size_t)s * 512 + off];
    ushort4 vv = *(const ushort4*)&kvb[(size_t)s * 512 + 256 + off];
    float e0=bf2f(ev.x), e1=bf2f(ev.y), e2=bf2f(ev.z), e3=bf2f(ev.w);
    float p = q.x*(bf2f(kk.x)+e0) + q.y*(bf2f(kk.y)+e1) + q.z*(bf2f(kk.z)+e2) + q.w*(bf2f(kk.w)+e3);
    p += __shfl_xor(p, 1); p += __shfl_xor(p, 2); p += __shfl_xor(p, 4);
    p *= 0.17677669529663687f;   // 1/sqrt(32)
    const float mn = fmaxf(m, p);
    const float sc = __expf(m - mn), w = __expf(p - mn);
    d = d * sc + w;
    a0 = a0 * sc + w * (bf2f(vv.x) + e0);
    a1 = a1 * sc + w * (bf2f(vv.y) + e1);
    a2 = a2 * sc + w * (bf2f(vv.z) + e2);
    a3 = a3 * sc + w * (bf2f(vv.w) + e3);
    m = mn;
  };

  int i = beg;
  for (; i + 3 < end; i += 4) {
    step(i,     m0, d0, x00, x01, x02, x03);
    step(i + 1, m1, d1, x10, x11, x12, x13);
    step(i + 2, m2, d2, x20, x21, x22, x23);
    step(i + 3, m3, d3, x30, x31, x32, x33);
  }
  for (; i < end; ++i) step(i, m0, d0, x00, x01, x02, x03);

  auto merge = [&](float& m, float& d, float& a0, float& a1, float& a2, float& a3,
                   float mB, float dB, float b0, float b1, float b2, float b3) {
    if (mB == -INFINITY) return;
    const float M = fmaxf(m, mB);
    const float sA = __expf(m - M), sB = __expf(mB - M);
    d = d * sA + dB * sB;
    a0 = a0 * sA + b0 * sB; a1 = a1 * sA + b1 * sB;
    a2 = a2 * sA + b2 * sB; a3 = a3 * sA + b3 * sB;
    m = M;
  };
  merge(m0, d0, x00, x01, x02, x03, m1, d1, x10, x11, x12, x13);
  merge(m2, d2, x20, x21, x22, x23, m3, d3, x30, x31, x32, x33);
  merge(m0, d0, x00, x01, x02, x03, m2, d2, x20, x21, x22, x23);

  const float inv = 1.f / (d0 + 1e-16f);
  const float4 sk = *(const float4*)&sf[(size_t)n * 256 + off];
  float o0 = fmaxf(x00 * inv + sk.x, 0.f);
  float o1 = fmaxf(x01 * inv + sk.y, 0.f);
  float o2 = fmaxf(x02 * inv + sk.z, 0.f);
  float o3 = fmaxf(x03 * inv + sk.w, 0.f);
  int rt = n >> 6, rf = (n >> 4) & 3, ir = n & 15;
  int kg = (lane & 7) >> 1, jj = 4 * (lane & 1);
  ushort4 w4;
  w4.x = f2bf(o0); w4.y = f2bf(o1); w4.z = f2bf(o2); w4.w = f2bf(o3);
  *(ushort4*)&ha[(size_t)rt * 16384 + h * 2048 + rf * 512 + (ir + 16 * kg) * 8 + jj] = w4;
}

// ---------------- attention layer 2: 4 independent online states ----------------
__global__ __launch_bounds__(64)
void attn2_kernel(const float* __restrict__ qkvs2, const unsigned short* __restrict__ e2b,
                  const int* __restrict__ srcs, const int* __restrict__ rowptr,
                  float* __restrict__ outp) {
  const int n = blockIdx.x;
  const int tid = threadIdx.x;
  const int c = tid & 31;
  const int beg = rowptr[n], end = rowptr[n + 1];
  const float qv = qkvs2[(size_t)n * 128 + c];

  float m0=-INFINITY,d0=0,x0=0;
  float m1=-INFINITY,d1=0,x1=0;
  float m2=-INFINITY,d2=0,x2=0;
  float m3=-INFINITY,d3=0,x3=0;

  auto step = [&](int i, float& m, float& d, float& a) {
    const int s = srcs[i];
    const float ev = bf2f(e2b[(size_t)i * 32 + c]);
    float p = qv * (qkvs2[(size_t)s * 128 + 32 + c] + ev);
    const float v = qkvs2[(size_t)s * 128 + 64 + c] + ev;
#pragma unroll
    for (int off = 16; off; off >>= 1) p += __shfl_xor(p, off);
    p *= 0.17677669529663687f;
    const float mn = fmaxf(m, p);
    const float sc = __expf(m - mn), w = __expf(p - mn);
    d = d * sc + w; a = a * sc + w * v; m = mn;
  };

  int i = beg;
  for (; i + 3 < end; i += 4) {
    step(i, m0, d0, x0);
    step(i + 1, m1, d1, x1);
    step(i + 2, m2, d2, x2);
    step(i + 3, m3, d3, x3);
  }
  for (; i < end; ++i) step(i, m0, d0, x0);

  auto merge = [&](float& m, float& d, float& a, float mB, float dB, float b) {
    if (mB == -INFINITY) return;
    const float M = fmaxf(m, mB);
    const float sA = __expf(m - M), sB = __expf(mB - M);
    d = d * sA + dB * sB; a = a * sA + b * sB; m = M;
  };
  merge(m0, d0, x0, m1, d1, x1);
  merge(m2, d2, x2, m3, d3, x3);
  merge(m0, d0, x0, m2, d2, x2);

  if (tid < 32) {
    float o = x0 / (d0 + 1e-16f) + qkvs2[(size_t)n * 128 + 96 + c];
    outp[(size_t)n * 32 + c] = fmaxf(o, 0.f);
  }
}

// ---------------- launcher ----------------
extern "C" void kernel_launch(void* const* d_in, const int* in_sizes, int n_in,
                              void* d_out, int out_size, void* d_ws, size_t ws_size,
                              hipStream_t stream) {
  const float* x   = (const float*)d_in[0];
  const float* lu  = (const float*)d_in[1];
  const int*   ei  = (const int*)d_in[2];
  const float* tt  = (const float*)d_in[3];
  const float* msg = (const float*)d_in[4];
  const float* tw  = (const float*)d_in[5];
  const float* tb  = (const float*)d_in[6];
  const float* Wq1 = (const float*)d_in[7];  const float* bq1 = (const float*)d_in[8];
  const float* Wk1 = (const float*)d_in[9];  const float* bk1 = (const float*)d_in[10];
  const float* Wv1 = (const float*)d_in[11]; const float* bv1 = (const float*)d_in[12];
  const float* We1 = (const float*)d_in[13];
  const float* Ws1 = (const float*)d_in[14]; const float* bs1 = (const float*)d_in[15];
  const float* Wq2 = (const float*)d_in[16]; const float* bq2 = (const float*)d_in[17];
  const float* Wk2 = (const float*)d_in[18]; const float* bk2 = (const float*)d_in[19];
  const float* Wv2 = (const float*)d_in[20]; const float* bv2 = (const float*)d_in[21];
  const float* We2 = (const float*)d_in[22];
  const float* Ws2 = (const float*)d_in[23]; const float* bs2 = (const float*)d_in[24];

  const int* srcp = ei;
  const int* dstp = ei + N_EDGES;

  char* p = (char*)d_ws;
  auto alloc = [&](size_t bytes) -> char* {
    char* r = p;
    p += (bytes + 255) & ~(size_t)255;
    return r;
  };
  int*   deg     = (int*)alloc((size_t)N_NODES * 4);
  int*   fill    = (int*)alloc((size_t)N_NODES * 4);
  int*   rowptr  = (int*)alloc((size_t)(N_NODES + 1) * 4);
  int*   sortpos = (int*)alloc((size_t)N_EDGES * 4);
  int*   srcs    = (int*)alloc((size_t)N_EDGES * 4);
  float* rel     = (float*)alloc((size_t)N_EDGES * 4);
  unsigned short* xa   = (unsigned short*)alloc((size_t)RT1 * 32768);
  unsigned short* W1f  = (unsigned short*)alloc((size_t)8 * 64 * 1024);
  unsigned short* We1f = (unsigned short*)alloc((size_t)8 * 16 * 1024);
  unsigned short* W2f  = (unsigned short*)alloc((size_t)8 * 8 * 1024);
  unsigned short* We2f = (unsigned short*)alloc((size_t)8 * 4 * 1024);
  float* bcat1  = (float*)alloc(1024 * 4);
  float* bcat2  = (float*)alloc(128 * 4);
  float* qf     = (float*)alloc((size_t)N_NODES * 256 * 4);
  unsigned short* kvb = (unsigned short*)alloc((size_t)N_NODES * 512 * 2);
  float* sf     = (float*)alloc((size_t)N_NODES * 256 * 4);
  unsigned short* e1b = (unsigned short*)alloc((size_t)N_EDGES * 256 * 2);   // 82 MB
  unsigned short* ha  = (unsigned short*)alloc((size_t)RT1 * 32768);
  float* qkvs2  = (float*)alloc((size_t)N_NODES * 128 * 4);
  unsigned short* e2b = (unsigned short*)alloc((size_t)N_EDGES * 32 * 2);
  float* outp   = (float*)d_out;

  hipMemsetAsync(deg, 0, (size_t)N_NODES * 4, stream);
  hipMemsetAsync(fill, 0, (size_t)N_NODES * 4, stream);
  hipMemsetAsync(ha + (size_t)(RT1 - 1) * 16384, 0, 32768, stream);  // zero pad rows 10000-10047

  prep1_kernel<<<625, 256, 0, stream>>>(lu, srcp, dstp, tt, rel, deg, N_EDGES);
  scan_kernel<<<1, 1024, 0, stream>>>(deg, rowptr, N_NODES);
  scatter_kernel<<<625, 256, 0, stream>>>(srcp, dstp, rowptr, fill, sortpos, srcs, N_EDGES);

  conv_all_kernel<<<ceildiv(CONVX_T + 369792, 256), 256, 0, stream>>>(
      x, xa, Wq1, Wk1, Wv1, Ws1, We1, Wq2, Wk2, Wv2, Ws2, We2,
      bq1, bk1, bv1, bs1, bq2, bk2, bv2, bs2,
      W1f, We1f, W2f, We2f, bcat1, bcat2);

  // merged: 2500 edge blocks + 628 node1 blocks, software-pipelined K-loop
  big_gemm<<<RTE + RT1 * 4, 512, 0, stream>>>(
      xa, W1f, bcat1, qf, kvb, sf, We1f, We2f, e1b, e2b,
      rel, tw, tb, msg, sortpos);

  attn1_kernel<<<N_NODES, 64, 0, stream>>>(qf, kvb, sf, e1b, srcs, rowptr, ha);
  gemm_node2<<<ceildiv(RT1, 2), 256, 0, stream>>>(ha, W2f, bcat2, qkvs2);
  attn2_kernel<<<N_NODES, 64, 0, stream>>>(qkvs2, e2b, srcs, rowptr, outp);
}